// Round 5
// baseline (405.036 us; speedup 1.0000x reference)
//
#include <hip/hip_runtime.h>
#include <math.h>

// ===========================================================================
// PCSQCNN fully fused: FRQI encode -> [QFT2D -> mux -> IQFT2D -> pool]^3
//                      -> |.|^2 -> linear
//
// Round 10: k1..k5 fused into ONE kernel (kfuse); 32 float2 state/thread.
// Round 11: waves_per_eu(4,4)        -> no effect (VGPR 64, scratch stays).
// Round 12: call-free __sinf/__cosf  -> no effect.
// Round 13: hand-scalarized state    -> no effect. VGPR *exactly* 64 in all
//   variants => it's a BUDGET: 512/64 = 8 waves/EU target. Cause found:
//   LDS was dynamic (extern __shared__) -> compiler sees LDS=0 -> occupancy
//   heuristic targets 8 waves/EU -> 64-VGPR cap -> whole state forced to
//   scratch (the ~130-160 MB of "HBM" traffic = scratch leaking through L2).
//   Also: 66 KB LDS does NOT pin 1 WG/CU on MI355X (160 KiB/CU, 2 WGs fit).
//
// Round 14 (this round): STATIC __shared__ padded past 80 KiB.
//   Xp[10240] + Yp[10240] + tw[64] = 82,432 B > 163,840/2  =>
//   (a) compile-time occupancy = 1 WG/CU = 4 waves/EU -> VGPR budget 128;
//   (b) runtime placement 1 WG/CU (nothing else could have shared anyway).
//   Launch drops dynamic-LDS arg. All arithmetic/order byte-identical.
//
// U tables (k0): U0 transposed [y_st][x_st]; U1 unchanged;
// U2 stored [yam][cx][cy][xam] so all mux loads are 128B-contiguous/thread.
// Custom ownerships:
//   F  = {2j, 2j+1, 64+2j, 64+2j+1}
//   F4 = {s0*32+m, +16, +64, +80}, s0=j>>4, m=j&15
// ===========================================================================

#define PI_F 3.14159265358979323846f
#define P_ 128

__device__ __forceinline__ float2 cmul(float2 a, float2 b) {
    return make_float2(a.x * b.x - a.y * b.y, a.x * b.y + a.y * b.x);
}
__device__ __forceinline__ float2 cadd(float2 a, float2 b) {
    return make_float2(a.x + b.x, a.y + b.y);
}
__device__ __forceinline__ float2 scl(float2 a, float s) {
    return make_float2(a.x * s, a.y * s);
}
// DIF butterfly: u' = u+v ; v' = (u-v)*w
__device__ __forceinline__ void bfly_dif(float2& u, float2& v, float2 w) {
    float tx = u.x - v.x, ty = u.y - v.y;
    u.x += v.x; u.y += v.y;
    v.x = tx * w.x - ty * w.y;
    v.y = tx * w.y + ty * w.x;
}
__device__ __forceinline__ void bfly_dif1(float2& u, float2& v) {
    float tx = u.x - v.x, ty = u.y - v.y;
    u.x += v.x; u.y += v.y;
    v.x = tx; v.y = ty;
}
// DIT inverse butterfly: t = v*conj(w); u' = u+t ; v' = u-t
__device__ __forceinline__ void bfly_dit(float2& u, float2& v, float2 w) {
    float tx = v.x * w.x + v.y * w.y, ty = v.y * w.x - v.x * w.y;
    v.x = u.x - tx; v.y = u.y - ty;
    u.x += tx; u.y += ty;
}
__device__ __forceinline__ void bfly_dit1(float2& u, float2& v) {
    float tx = v.x, ty = v.y;
    v.x = u.x - tx; v.y = u.y - ty;
    u.x += tx; u.y += ty;
}

constexpr int clog2(int v) { return v <= 1 ? 0 : 1 + clog2(v >> 1); }

// LDS exchange address: line L (0..63 per plane), idx 0..127, XOR bank
// swizzle (bijective; GF(2)-rank-verified for all ownership patterns).
__device__ __forceinline__ int pf(int L, int idx) {
    int m = ((idx & 32) ? 13 : 0) ^ ((idx & 64) ? 22 : 0);
    return L * P_ + (idx ^ m);
}

// Ownership: segment size N (<=128), stride S. Thread j (0..31 per line) owns
// idx[q] = seg*N + 4S*(jj/S) + (jj%S) + S*q.  o = jj%S (twiddle low part).
template <int N, int S>
__device__ __forceinline__ void oidx(int j, int i[4], int& o) {
    constexpr int TPS = N / 4;
    constexpr int LT = clog2(TPS);
    int s = j >> LT;
    int jj = j & (TPS - 1);
    o = jj & (S - 1);
    int base = s * N + ((jj & ~(S - 1)) << 2) + o;
    i[0] = base; i[1] = base + S; i[2] = base + 2 * S; i[3] = base + 3 * S;
}

// Two DIF levels h=2S then h=S on r[0..3] (ownership stride S)
template <int S>
__device__ __forceinline__ void dif_pair(float2 r[4], int o, const float2* tw) {
    bfly_dif(r[0], r[2], tw[o * (32 / S)]);
    bfly_dif(r[1], r[3], tw[(o + S) * (32 / S)]);
    float2 wc = tw[o * (64 / S)];
    bfly_dif(r[0], r[1], wc);
    bfly_dif(r[2], r[3], wc);
}
// Two DIT levels h=S then h=2S
template <int S>
__device__ __forceinline__ void dit_pair(float2 r[4], int o, const float2* tw) {
    float2 wc = tw[o * (64 / S)];
    bfly_dit(r[0], r[1], wc);
    bfly_dit(r[2], r[3], wc);
    bfly_dit(r[0], r[2], tw[o * (32 / S)]);
    bfly_dit(r[1], r[3], tw[(o + S) * (32 / S)]);
}

// SoA store/load of one float2
__device__ __forceinline__ void stf(float* bx, float* by, int a, float2 v) {
    bx[a] = v.x; by[a] = v.y;
}
__device__ __forceinline__ float2 ldf(const float* bx, const float* by, int a) {
    return make_float2(bx[a], by[a]);
}

// One exchange round for a line pair (A -> LDS line la, B -> line lb).
// Crew = 32 consecutive lanes of one wave -> wave_barrier suffices.
__device__ __forceinline__ void xch2(float* Xp, float* Yp, int la, int lb,
                                     const int* iw, const int* ir,
                                     float2 A[4], float2 B[4]) {
    stf(Xp, Yp, pf(la, iw[0]), A[0]); stf(Xp, Yp, pf(lb, iw[0]), B[0]);
    stf(Xp, Yp, pf(la, iw[1]), A[1]); stf(Xp, Yp, pf(lb, iw[1]), B[1]);
    stf(Xp, Yp, pf(la, iw[2]), A[2]); stf(Xp, Yp, pf(lb, iw[2]), B[2]);
    stf(Xp, Yp, pf(la, iw[3]), A[3]); stf(Xp, Yp, pf(lb, iw[3]), B[3]);
    __builtin_amdgcn_wave_barrier();
    A[0] = ldf(Xp, Yp, pf(la, ir[0])); B[0] = ldf(Xp, Yp, pf(lb, ir[0]));
    A[1] = ldf(Xp, Yp, pf(la, ir[1])); B[1] = ldf(Xp, Yp, pf(lb, ir[1]));
    A[2] = ldf(Xp, Yp, pf(la, ir[2])); B[2] = ldf(Xp, Yp, pf(lb, ir[2]));
    A[3] = ldf(Xp, Yp, pf(la, ir[3])); B[3] = ldf(Xp, Yp, pf(lb, ir[3]));
    __builtin_amdgcn_wave_barrier();
}

// Full 8-line crew exchange; rounds: (r0,r4), (r1,r5), (r2,r6), (r3,r7).
template <int NW, int SW, int NR, int SR>
__device__ __forceinline__ int xc8(float* Xp, float* Yp, int la, int lb, int j,
                                   float2 A0[4], float2 A1[4], float2 A2[4],
                                   float2 A3[4], float2 B0[4], float2 B1[4],
                                   float2 B2[4], float2 B3[4]) {
    int iw[4], ow, ir[4], orr;
    oidx<NW, SW>(j, iw, ow);
    oidx<NR, SR>(j, ir, orr);
    (void)ow;
    xch2(Xp, Yp, la, lb, iw, ir, A0, B0);
    xch2(Xp, Yp, la, lb, iw, ir, A1, B1);
    xch2(Xp, Yp, la, lb, iw, ir, A2, B2);
    xch2(Xp, Yp, la, lb, iw, ir, A3, B3);
    return orr;
}

__device__ __forceinline__ void mkF(int j, int* i) {
    i[0] = 2 * j; i[1] = 2 * j + 1; i[2] = 64 + 2 * j; i[3] = 65 + 2 * j;
}
__device__ __forceinline__ void mkF4(int j, int* i) {
    int b = (j >> 4) * 32 + (j & 15);
    i[0] = b; i[1] = b + 16; i[2] = b + 64; i[3] = b + 80;
}

// 2x2 multiplex on feature pair (a = f0, b = f1) with table entry U[0..3]
__device__ __forceinline__ void muxop(const float2* __restrict__ U,
                                      float2& a, float2& b) {
    float2 p0 = a, p1 = b;
    a = cadd(cmul(U[0], p0), cmul(U[1], p1));
    b = cadd(cmul(U[2], p0), cmul(U[3], p1));
}

// ---- 8-way expansion helpers (state = named arrays r0..r7) ----------------
#define FOR8(OP) { OP(r0) OP(r1) OP(r2) OP(r3) OP(r4) OP(r5) OP(r6) OP(r7) }
#define DIF8(S, O) { dif_pair<S>(r0, O, tw); dif_pair<S>(r1, O, tw); \
    dif_pair<S>(r2, O, tw); dif_pair<S>(r3, O, tw); dif_pair<S>(r4, O, tw); \
    dif_pair<S>(r5, O, tw); dif_pair<S>(r6, O, tw); dif_pair<S>(r7, O, tw); }
#define DIT8(S, O) { dit_pair<S>(r0, O, tw); dit_pair<S>(r1, O, tw); \
    dit_pair<S>(r2, O, tw); dit_pair<S>(r3, O, tw); dit_pair<S>(r4, O, tw); \
    dit_pair<S>(r5, O, tw); dit_pair<S>(r6, O, tw); dit_pair<S>(r7, O, tw); }
#define XC8(NW, SW, NR, SR) \
    xc8<NW, SW, NR, SR>(Xp, Yp, la, lb, j, r0, r1, r2, r3, r4, r5, r6, r7)
#define XCHC(IW, IR) { xch2(Xp, Yp, la, lb, IW, IR, r0, r4); \
    xch2(Xp, Yp, la, lb, IW, IR, r1, r5); \
    xch2(Xp, Yp, la, lb, IW, IR, r2, r6); \
    xch2(Xp, Yp, la, lb, IW, IR, r3, r7); }

// per-line op shapes (wA/wB/wC/sc_ taken from enclosing scope)
#define OP_H1F(R)  { bfly_dif1(R[0], R[1]); bfly_dif1(R[2], R[3]); }
#define OP_H1T(R)  { bfly_dit1(R[0], R[1]); bfly_dit1(R[2], R[3]); }
#define OP_H64(R)  { bfly_dit(R[0], R[2], wA); bfly_dit(R[1], R[3], wB); }
#define OP_FH(R)   { bfly_dif(R[0], R[1], wC); bfly_dif(R[2], R[3], wC); }
#define OP_H16P(R) { bfly_dit(R[0], R[1], wC); bfly_dit(R[2], R[3], wC); }
#define OP_SC(R)   { R[0] = scl(R[0], sc_); R[1] = scl(R[1], sc_); \
                     R[2] = scl(R[2], sc_); R[3] = scl(R[3], sc_); }

// register 4x4 transpose (pure renaming), per f-block
#define XPOSE_BLK(A, B, C, D) { float2 t_; \
    t_ = A[1]; A[1] = B[0]; B[0] = t_; \
    t_ = A[2]; A[2] = C[0]; C[0] = t_; \
    t_ = A[3]; A[3] = D[0]; D[0] = t_; \
    t_ = B[2]; B[2] = C[1]; C[1] = t_; \
    t_ = B[3]; B[3] = D[1]; D[1] = t_; \
    t_ = C[3]; C[3] = D[2]; D[2] = t_; }
#define XPOSE44() { XPOSE_BLK(r0, r1, r2, r3) XPOSE_BLK(r4, r5, r6, r7) }

// Transpose A chunk: store pair (RA,RB) at Y-positions isv, reload at new
// X-positions (MODE 0: Xl=j+32e ; MODE 1: Xl=2j+e). Rotation swizzle.
#define TPA_ST(R, XL) { const int Xl = (XL); \
    int a0 = Xl * P_ + ((isv[0] + Xl) & 127); Xp[a0] = R[0].x; Yp[a0] = R[0].y; \
    int a1 = Xl * P_ + ((isv[1] + Xl) & 127); Xp[a1] = R[1].x; Yp[a1] = R[1].y; \
    int a2 = Xl * P_ + ((isv[2] + Xl) & 127); Xp[a2] = R[2].x; Yp[a2] = R[2].y; \
    int a3 = Xl * P_ + ((isv[3] + Xl) & 127); Xp[a3] = R[3].x; Yp[a3] = R[3].y; }
#define TPA_LD(R, XL) { const int Xl = (XL); \
    R[0] = make_float2(Xp[Xl * P_ + ((g      + Xl) & 127)], Yp[Xl * P_ + ((g      + Xl) & 127)]); \
    R[1] = make_float2(Xp[Xl * P_ + ((g + 32 + Xl) & 127)], Yp[Xl * P_ + ((g + 32 + Xl) & 127)]); \
    R[2] = make_float2(Xp[Xl * P_ + ((g + 64 + Xl) & 127)], Yp[Xl * P_ + ((g + 64 + Xl) & 127)]); \
    R[3] = make_float2(Xp[Xl * P_ + ((g + 96 + Xl) & 127)], Yp[Xl * P_ + ((g + 96 + Xl) & 127)]); }
#define TPA_CHUNK(RA, RB, XLA, XLB) { \
    __syncthreads(); \
    TPA_ST(RA, g) TPA_ST(RB, g + 32) \
    __syncthreads(); \
    TPA_LD(RA, XLA) TPA_LD(RB, XLB) }

// Transpose B chunk: store pair at X-lines from isv, reload at Y-pos idv.
#define TPB_ST(R, ISL) { const int Xl = (ISL) & 63; \
    int a0 = Xl * P_ + ((g      + Xl) & 127); Xp[a0] = R[0].x; Yp[a0] = R[0].y; \
    int a1 = Xl * P_ + ((g + 32 + Xl) & 127); Xp[a1] = R[1].x; Yp[a1] = R[1].y; \
    int a2 = Xl * P_ + ((g + 64 + Xl) & 127); Xp[a2] = R[2].x; Yp[a2] = R[2].y; \
    int a3 = Xl * P_ + ((g + 96 + Xl) & 127); Xp[a3] = R[3].x; Yp[a3] = R[3].y; }
#define TPB_LD(R, XL) { const int Xl = (XL); \
    R[0] = make_float2(Xp[Xl * P_ + ((idv[0] + Xl) & 127)], Yp[Xl * P_ + ((idv[0] + Xl) & 127)]); \
    R[1] = make_float2(Xp[Xl * P_ + ((idv[1] + Xl) & 127)], Yp[Xl * P_ + ((idv[1] + Xl) & 127)]); \
    R[2] = make_float2(Xp[Xl * P_ + ((idv[2] + Xl) & 127)], Yp[Xl * P_ + ((idv[2] + Xl) & 127)]); \
    R[3] = make_float2(Xp[Xl * P_ + ((idv[3] + Xl) & 127)], Yp[Xl * P_ + ((idv[3] + Xl) & 127)]); }
#define TPB_CHUNK(RA, RB, ISA, ISB) { \
    __syncthreads(); \
    TPB_ST(RA, ISA) TPB_ST(RB, ISB) \
    __syncthreads(); \
    TPB_LD(RA, g) TPB_LD(RB, g + 32) }

// ---------------------------------------------------------------------------
// K0: precompute multiplex U tables, pre-permuted by bit-reversal.
//   U0: TRANSPOSED  idx = y_st*128 + x_st
//   U1: unchanged   idx = ((cx*2+cy)*64 + xam)*64 + yam
//   U2: TRANSPOSED  idx = ((yam*2 + cx)*2 + cy)*32 + xam
// ---------------------------------------------------------------------------
__global__ __launch_bounds__(256) void k0_prep(const float* __restrict__ mux0,
                                               const float* __restrict__ mux1,
                                               const float* __restrict__ mux2,
                                               float2* __restrict__ U0,
                                               float2* __restrict__ U1,
                                               float2* __restrict__ U2) {
    int t = blockIdx.x * 256 + threadIdx.x;
    const float* src;
    float2* dst;
    if (t < 16384) {
        int xb = t >> 7, yb = t & 127;
        int rx = __brev((unsigned)xb) >> 25;
        int ry = __brev((unsigned)yb) >> 25;
        src = mux0 + ((size_t)rx * 128 + ry) * 3;
        dst = U0 + ((size_t)yb * 128 + xb) * 4;
    } else if (t < 32768) {
        int u = t - 16384;
        int yam = u & 63, xam = (u >> 6) & 63, cy = (u >> 12) & 1, cx = (u >> 13) & 1;
        int rx = __brev((unsigned)xam) >> 26;
        int ry = __brev((unsigned)yam) >> 26;
        src = mux1 + ((size_t)(((cx * 2 + cy) * 64 + rx) * 64 + ry)) * 3;
        dst = U1 + (size_t)u * 4;
    } else if (t < 36864) {
        int u = t - 32768;
        int yam = u & 31, xam = (u >> 5) & 31, cy = (u >> 10) & 1, cx = (u >> 11) & 1;
        int rx = __brev((unsigned)xam) >> 27;
        int ry = __brev((unsigned)yam) >> 27;
        src = mux2 + ((size_t)(((cx * 2 + cy) * 32 + rx) * 32 + ry)) * 3;
        dst = U2 + ((size_t)(((yam * 2 + cx) * 2 + cy) * 32 + xam)) * 4;
    } else {
        return;
    }
    float ax = src[0], ay = src[1], az = src[2];
    float r = sqrtf(ax * ax + ay * ay + az * az + 1e-20f);
    float cr = cosf(r);
    float snr = sinf(r) / r;
    dst[0] = make_float2(cr, -az * snr);
    dst[1] = make_float2(-ay * snr, -ax * snr);
    dst[2] = make_float2(ay * snr, -ax * snr);
    dst[3] = make_float2(cr, az * snr);
}

// ---------------------------------------------------------------------------
// KFUSE: whole pipeline per image. Block = 1024 threads (32 crews x 32).
// State: 8 named 4-float2 arrays. STATIC LDS, padded past 80 KiB so the
// compiler's occupancy model sees 1 WG/CU (4 waves/EU) -> 128-VGPR budget.
// Only the first 8192 floats of each plane are addressed; the pad is the
// occupancy pin (the arrays are referenced, so they are fully allocated).
// ---------------------------------------------------------------------------
__global__ __attribute__((amdgpu_flat_work_group_size(1024, 1024)))
__attribute__((amdgpu_waves_per_eu(4, 4)))
void kfuse(const float* __restrict__ img,
           const float2* __restrict__ U0,
           const float2* __restrict__ U1,
           const float2* __restrict__ U2,
           float* __restrict__ prob) {
    __shared__ float XpS[10240];            // 8192 used + 2048 occupancy pad
    __shared__ float YpS[10240];            // 8192 used + 2048 occupancy pad
    __shared__ float2 twS[64];
    float* Xp = XpS;
    float* Yp = YpS;
    float2* tw = twS;                       // total 82,432 B > 160 KiB / 2

    const int tid = threadIdx.x;
    const int b = blockIdx.x;
    const int g = tid >> 5;
    const int j = tid & 31;
    const int la = 2 * g, lb = 2 * g + 1;

    if (tid < 64) {
        float ang = -(2.0f * PI_F / 128.0f) * (float)tid;  // |ang| < 2pi
        tw[tid] = make_float2(__cosf(ang), __sinf(ang));
    }

    float2 r0[4], r1[4], r2[4], r3[4], r4[4], r5[4], r6[4], r7[4];
    int o;

    // ================= pass 1 (Y): FRQI encode + FFT_Y128 =================
    {
        const float* ib = img + (size_t)b * 16384;
        const float S128 = 1.0f / 128.0f;
#define ENC_K(K, RA, RB) { \
        const float* ip = ib + (g + 32 * (K)) * 128; \
        { float ang = 0.5f * PI_F * ip[j];      RA[0] = make_float2(__cosf(ang) * S128, 0.0f); RB[0] = make_float2(__sinf(ang) * S128, 0.0f); } \
        { float ang = 0.5f * PI_F * ip[j + 32]; RA[1] = make_float2(__cosf(ang) * S128, 0.0f); RB[1] = make_float2(__sinf(ang) * S128, 0.0f); } \
        { float ang = 0.5f * PI_F * ip[j + 64]; RA[2] = make_float2(__cosf(ang) * S128, 0.0f); RB[2] = make_float2(__sinf(ang) * S128, 0.0f); } \
        { float ang = 0.5f * PI_F * ip[j + 96]; RA[3] = make_float2(__cosf(ang) * S128, 0.0f); RB[3] = make_float2(__sinf(ang) * S128, 0.0f); } }
        ENC_K(0, r0, r4) ENC_K(1, r1, r5) ENC_K(2, r2, r6) ENC_K(3, r3, r7)
#undef ENC_K
    }
    __syncthreads();  // tw visible
    DIF8(32, j)                                   // h=64,32
    o = XC8(128, 32, 128, 8);
    DIF8(8, o)                                    // h=16,8
    o = XC8(128, 8, 128, 2);
    DIF8(2, o)                                    // h=4,2
    o = XC8(128, 2, 128, 1);
    FOR8(OP_H1F)                                  // h=1

    // ================= T_A1 (MODE 0) =================
    {
        int isv[4] = {4 * j, 4 * j + 1, 4 * j + 2, 4 * j + 3};
        TPA_CHUNK(r0, r1, j, j + 32)
        TPA_CHUNK(r2, r3, j, j + 32)
        TPA_CHUNK(r4, r5, j, j + 32)
        TPA_CHUNK(r6, r7, j, j + 32)
        __syncthreads();
        XPOSE44()
    }

    // ====== pass 2 (X): FFT_X128 -> M0 -> IFFT_X128 -> FFT_X64 ======
    DIF8(32, j)
    o = XC8(128, 32, 128, 8);
    DIF8(8, o)
    o = XC8(128, 8, 128, 2);
    DIF8(2, o)
    o = XC8(128, 2, 128, 1);
    FOR8(OP_H1F)
    // M0 at x_st = 4j+q, y_st = g+32k (register-local f pair)
    {
#define MUX0_K(K, RA, RB) { \
        const float2* Ub = U0 + ((size_t)(g + 32 * (K)) * 128 + 4 * j) * 4; \
        muxop(Ub + 0, RA[0], RB[0]); muxop(Ub + 4,  RA[1], RB[1]); \
        muxop(Ub + 8, RA[2], RB[2]); muxop(Ub + 12, RA[3], RB[3]); }
        MUX0_K(0, r0, r4) MUX0_K(1, r1, r5) MUX0_K(2, r2, r6) MUX0_K(3, r3, r7)
#undef MUX0_K
    }
    // IFFT_X128: [1,2] -> [4,8] -> [16,32] -> [64]
    DIT8(1, 0)
    o = XC8(128, 1, 128, 4);
    DIT8(4, o)
    o = XC8(128, 4, 128, 16);
    DIT8(16, o)
    o = XC8(128, 16, 128, 32);
    { const float2 wA = tw[o], wB = tw[o + 32]; FOR8(OP_H64) }   // h=64
    { const float2 wC = tw[2 * o]; FOR8(OP_FH) }                 // FFT64 h=32
    o = XC8(128, 32, 64, 8);
    DIF8(8, o)                                    // FFT64 h=16,8
    o = XC8(64, 8, 64, 2);
    DIF8(2, o)                                    // h=4,2
    {   // -> F ownership (needed by T_B1)
        int iw_[4], o_, ir_[4];
        oidx<64, 2>(j, iw_, o_);
        mkF(j, ir_);
        XCHC(iw_, ir_)
    }
    FOR8(OP_H1F)                                  // h=1
    { const float sc_ = 1.0f / 128.0f; FOR8(OP_SC) }  // IFFT128 norm

    // ================= T_B1 =================
    {
        int isv[4], idv[4];
        mkF(j, isv);
        idv[0] = 4 * j; idv[1] = 4 * j + 1; idv[2] = 4 * j + 2; idv[3] = 4 * j + 3;
        XPOSE44()
        TPB_CHUNK(r0, r1, isv[0], isv[1])
        TPB_CHUNK(r2, r3, isv[2], isv[3])
        TPB_CHUNK(r4, r5, isv[0], isv[1])
        TPB_CHUNK(r6, r7, isv[2], isv[3])
        __syncthreads();
    }

    // == pass 3 (Y): IFFT_Y128 -> FFT_Y64 -> M1 -> IFFT_Y64 -> FFT_Y32 ==
    DIT8(1, 0)
    o = XC8(128, 1, 128, 4);
    DIT8(4, o)
    o = XC8(128, 4, 128, 16);
    DIT8(16, o)
    o = XC8(128, 16, 128, 32);
    { const float2 wA = tw[o], wB = tw[o + 32]; FOR8(OP_H64) }
    { const float2 wC = tw[2 * o]; FOR8(OP_FH) }
    o = XC8(128, 32, 64, 8);
    DIF8(8, o)
    o = XC8(64, 8, 64, 2);
    DIF8(2, o)
    o = XC8(64, 2, 64, 1);
    FOR8(OP_H1F)
    // M1: y_st = s*64 + 4jj + q; lines x_st = g+32k
    {
        const int s = j >> 4, jj = j & 15;
#define MUX1_K(CX, KB, RA, RB) { \
        const int xam = g + 32 * (KB); \
        const float2* Ub = U1 + \
            ((size_t)(((((((CX) << 1) | s) << 6) | xam) << 6) | (4 * jj))) * 4; \
        muxop(Ub + 0, RA[0], RB[0]); muxop(Ub + 4,  RA[1], RB[1]); \
        muxop(Ub + 8, RA[2], RB[2]); muxop(Ub + 12, RA[3], RB[3]); }
        MUX1_K(0, 0, r0, r4) MUX1_K(0, 1, r1, r5)
        MUX1_K(1, 0, r2, r6) MUX1_K(1, 1, r3, r7)
#undef MUX1_K
    }
    // IFFT_Y64: [1,2] -> [4,8] -> [16,32]
    DIT8(1, 0)
    o = XC8(64, 1, 64, 4);
    DIT8(4, o)
    o = XC8(64, 4, 64, 16);
    DIT8(16, o)
    { const float2 wC = tw[4 * o]; FOR8(OP_FH) }  // fused FFT32 h=16
    o = XC8(64, 16, 32, 4);
    DIF8(4, o)                                    // FFT32 h=8,4
    o = XC8(32, 4, 32, 1);
    DIF8(1, 0)                                    // h=2,1
    { const float sc_ = 1.0f / 8192.0f; FOR8(OP_SC) }  // IFFT128*IFFT64

    // ================= T_A2 (MODE 1, dest positions = F) =================
    {
        int isv[4], o_;
        oidx<32, 1>(j, isv, o_);
        TPA_CHUNK(r0, r1, 2 * j, 2 * j + 1)
        TPA_CHUNK(r2, r3, 2 * j, 2 * j + 1)
        TPA_CHUNK(r4, r5, 2 * j, 2 * j + 1)
        TPA_CHUNK(r6, r7, 2 * j, 2 * j + 1)
        __syncthreads();
        XPOSE44()
    }

    // ====== pass 4 (X): IFFT_X64 -> FFT_X32 -> M2 -> IFFT_X32 ======
    FOR8(OP_H1T)                                  // h=1 at F (w=1)
    {
        int iw_[4], ir_[4], o_;
        mkF(j, iw_);
        oidx<64, 2>(j, ir_, o_);
        XCHC(iw_, ir_)
        o = o_;
    }
    DIT8(2, o)                                    // h=2,4
    o = XC8(64, 2, 64, 8);
    DIT8(8, o)                                    // h=8,16
    o = XC8(64, 8, 64, 16);
    { const float2 wA = tw[2 * o], wB = tw[2 * (o + 16)]; FOR8(OP_H64) }  // h=32
    { const float2 wC = tw[4 * o]; FOR8(OP_FH) }  // fused FFT32 h=16
    o = XC8(64, 16, 32, 4);
    DIF8(4, o)
    o = XC8(32, 4, 32, 1);
    DIF8(1, 0)
    // M2: x_st = s4*32 + 4jj8 + q; lines y_st = g+32k
    {
        const int s4 = j >> 3, jj8 = j & 7;
#define MUX2_K(KB, RA, RB) { \
        const float2* Ub = U2 + \
            ((size_t)((((g << 2) | ((s4 & 1) << 1) | (KB)) << 5) | (4 * jj8))) * 4; \
        muxop(Ub + 0, RA[0], RB[0]); muxop(Ub + 4,  RA[1], RB[1]); \
        muxop(Ub + 8, RA[2], RB[2]); muxop(Ub + 12, RA[3], RB[3]); }
        MUX2_K(0, r0, r4) MUX2_K(1, r1, r5) MUX2_K(0, r2, r6) MUX2_K(1, r3, r7)
#undef MUX2_K
    }
    // IFFT_X32: [1,2] -> [4,8] -> [16] (end at F4 for T_B2)
    DIT8(1, 0)
    o = XC8(32, 1, 32, 4);
    DIT8(4, o)
    {
        int iw_[4], o_, ir_[4];
        oidx<32, 4>(j, iw_, o_);
        mkF4(j, ir_);
        XCHC(iw_, ir_)
    }
    {
        const int m = j & 15;
        const float2 wC = tw[4 * m];
        FOR8(OP_H16P)                             // h=16
        const float sc_ = 1.0f / 2048.0f;         // IFFT64*IFFT32
        FOR8(OP_SC)
    }

    // ================= T_B2 =================
    {
        int isv[4], idv[4], o_;
        mkF4(j, isv);
        oidx<32, 1>(j, idv, o_);
        XPOSE44()
        TPB_CHUNK(r0, r1, isv[0], isv[1])
        TPB_CHUNK(r2, r3, isv[2], isv[3])
        TPB_CHUNK(r4, r5, isv[0], isv[1])
        TPB_CHUNK(r6, r7, isv[2], isv[3])
        __syncthreads();
    }

    // ========== pass 5 (Y): IFFT_Y32 + |.|^2 marginal ==========
    DIT8(1, 0)
    o = XC8(32, 1, 32, 4);
    DIT8(4, o)
    o = XC8(32, 4, 32, 8);
    { const float2 wA = tw[4 * o], wB = tw[4 * o + 32]; FOR8(OP_H64) }  // h=16
    // prob: sum over xc (in-thread lines) and yc (= j>>3, via shfl)
    {
#define SQ2(v) ((v).x * (v).x + (v).y * (v).y)
        float s00 = SQ2(r0[0]) + SQ2(r1[0]) + SQ2(r2[0]) + SQ2(r3[0]);
        float s01 = SQ2(r0[1]) + SQ2(r1[1]) + SQ2(r2[1]) + SQ2(r3[1]);
        float s02 = SQ2(r0[2]) + SQ2(r1[2]) + SQ2(r2[2]) + SQ2(r3[2]);
        float s03 = SQ2(r0[3]) + SQ2(r1[3]) + SQ2(r2[3]) + SQ2(r3[3]);
        float s10 = SQ2(r4[0]) + SQ2(r5[0]) + SQ2(r6[0]) + SQ2(r7[0]);
        float s11 = SQ2(r4[1]) + SQ2(r5[1]) + SQ2(r6[1]) + SQ2(r7[1]);
        float s12 = SQ2(r4[2]) + SQ2(r5[2]) + SQ2(r6[2]) + SQ2(r7[2]);
        float s13 = SQ2(r4[3]) + SQ2(r5[3]) + SQ2(r6[3]) + SQ2(r7[3]);
#undef SQ2
        s00 += __shfl_xor(s00, 8); s00 += __shfl_xor(s00, 16);
        s01 += __shfl_xor(s01, 8); s01 += __shfl_xor(s01, 16);
        s02 += __shfl_xor(s02, 8); s02 += __shfl_xor(s02, 16);
        s03 += __shfl_xor(s03, 8); s03 += __shfl_xor(s03, 16);
        s10 += __shfl_xor(s10, 8); s10 += __shfl_xor(s10, 16);
        s11 += __shfl_xor(s11, 8); s11 += __shfl_xor(s11, 16);
        s12 += __shfl_xor(s12, 8); s12 += __shfl_xor(s12, 16);
        s13 += __shfl_xor(s13, 8); s13 += __shfl_xor(s13, 16);
        if ((j >> 3) == 0) {
            const int jj = j & 7;
            const float C = 1.0f / 1024.0f;
            float2* pp = (float2*)(prob + (size_t)(b * 32 + g) * 64);
            pp[jj +  0] = make_float2(s00 * C, s10 * C);
            pp[jj +  8] = make_float2(s01 * C, s11 * C);
            pp[jj + 16] = make_float2(s02 * C, s12 * C);
            pp[jj + 24] = make_float2(s03 * C, s13 * C);
        }
    }
}

// ---------------------------------------------------------------------------
// K6: linear head, wave-shuffle reduction (unchanged).
// ---------------------------------------------------------------------------
__global__ __launch_bounds__(256) void k6_linear(const float* __restrict__ prob,
                                                 const float* __restrict__ W,
                                                 const float* __restrict__ bv,
                                                 float* __restrict__ out) {
    __shared__ float red[40];
    int b = blockIdx.x;
    int tid = threadIdx.x;
    float acc[10];
#pragma unroll
    for (int c = 0; c < 10; ++c) acc[c] = 0.0f;
    for (int j = tid; j < 2048; j += 256) {
        float p = prob[(size_t)b * 2048 + j];
#pragma unroll
        for (int c = 0; c < 10; ++c) acc[c] += p * W[c * 2048 + j];
    }
    int wv = tid >> 6, ln = tid & 63;
#pragma unroll
    for (int c = 0; c < 10; ++c) {
        float s = acc[c];
        for (int off = 32; off > 0; off >>= 1) s += __shfl_down(s, off);
        if (ln == 0) red[wv * 10 + c] = s;
    }
    __syncthreads();
    if (tid < 10)
        out[b * 10 + tid] =
            red[tid] + red[10 + tid] + red[20 + tid] + red[30 + tid] + bv[tid];
}

// ---------------------------------------------------------------------------
extern "C" void kernel_launch(void* const* d_in, const int* in_sizes, int n_in,
                              void* d_out, int out_size, void* d_ws,
                              size_t ws_size, hipStream_t stream) {
    const float* images = (const float*)d_in[0];
    const float* mux0 = (const float*)d_in[1];
    const float* mux1 = (const float*)d_in[2];
    const float* mux2 = (const float*)d_in[3];
    const float* W = (const float*)d_in[4];
    const float* bv = (const float*)d_in[5];
    float* out = (float*)d_out;

    float2* U0 = (float2*)d_ws;
    float2* U1 = U0 + 65536;
    float2* U2 = U1 + 65536;
    float* prob = (float*)(U2 + 16384);
    const size_t needed =
        (size_t)(65536 + 65536 + 16384) * sizeof(float2) +
        (size_t)512 * 2048 * sizeof(float);
    if (ws_size < needed) return;

    k0_prep<<<144, 256, 0, stream>>>(mux0, mux1, mux2, U0, U1, U2);
    kfuse<<<512, 1024, 0, stream>>>(images, U0, U1, U2, prob);
    k6_linear<<<512, 256, 0, stream>>>(prob, W, bv, out);
}

// Round 6
// 354.191 us; speedup vs baseline: 1.1436x; 1.1436x over previous
//
#include <hip/hip_runtime.h>
#include <math.h>

// ===========================================================================
// PCSQCNN fully fused: FRQI encode -> [QFT2D -> mux -> IQFT2D -> pool]^3
//                      -> |.|^2 -> linear
//
// Round 10: fused kfuse, state "in registers" (r[8][4]).
// Round 11: waves_per_eu(4,4)       -> null (VGPR 64, scratch stays).
// Round 12: call-free __sinf/__cosf -> null.
// Round 13: scalarized to r0..r7[4] -> null.
// Round 14: static 82KB LDS pin     -> null for VGPR; 1 WG/CU made it WORSE
//   (the 2nd WG had been hiding scratch latency).
// Round 15 (this round): ZERO-AGGREGATE kernel. Theory: the state arrays
//   were never promoted to SSA (aggregate allocas survive; occupancy
//   attributes were no-ops because pressure never materialized). Fix: 32
//   individually named float2 scalars v00..v73; helpers take float2&;
//   all index quads are named ints; everything macro-expanded. No local
//   arrays/aggregates anywhere in kfuse. Same arithmetic, same LDS
//   addressing, same barrier placement as rounds 13/14.
//
// U tables (k0): U0 transposed [y_st][x_st]; U1 unchanged;
// U2 stored [yam][cx][cy][xam] so mux loads are 128B-contiguous/thread.
// Ownerships: F = {2j,2j+1,64+2j,65+2j}; F4 = {fb,fb+16,fb+64,fb+80},
// fb=(j>>4)*32+(j&15).
// ===========================================================================

#define PI_F 3.14159265358979323846f
#define P_ 128

__device__ __forceinline__ float2 cmul(float2 a, float2 b) {
    return make_float2(a.x * b.x - a.y * b.y, a.x * b.y + a.y * b.x);
}
__device__ __forceinline__ float2 cadd(float2 a, float2 b) {
    return make_float2(a.x + b.x, a.y + b.y);
}
__device__ __forceinline__ float2 scl(float2 a, float s) {
    return make_float2(a.x * s, a.y * s);
}
__device__ __forceinline__ void bfly_dif(float2& u, float2& v, float2 w) {
    float tx = u.x - v.x, ty = u.y - v.y;
    u.x += v.x; u.y += v.y;
    v.x = tx * w.x - ty * w.y;
    v.y = tx * w.y + ty * w.x;
}
__device__ __forceinline__ void bfly_dif1(float2& u, float2& v) {
    float tx = u.x - v.x, ty = u.y - v.y;
    u.x += v.x; u.y += v.y;
    v.x = tx; v.y = ty;
}
__device__ __forceinline__ void bfly_dit(float2& u, float2& v, float2 w) {
    float tx = v.x * w.x + v.y * w.y, ty = v.y * w.x - v.x * w.y;
    v.x = u.x - tx; v.y = u.y - ty;
    u.x += tx; u.y += ty;
}
__device__ __forceinline__ void bfly_dit1(float2& u, float2& v) {
    float tx = v.x, ty = v.y;
    v.x = u.x - tx; v.y = u.y - ty;
    u.x += tx; u.y += ty;
}

constexpr int clog2(int v) { return v <= 1 ? 0 : 1 + clog2(v >> 1); }

// LDS exchange address: line L, idx 0..127, XOR bank swizzle (bijective).
__device__ __forceinline__ int pf(int L, int idx) {
    int m = ((idx & 32) ? 13 : 0) ^ ((idx & 64) ? 22 : 0);
    return L * P_ + (idx ^ m);
}

// Ownership (scalar outputs): thread j owns base + {0,1,2,3}*S within
// segment of size N; o = jj % S.
template <int N, int S>
__device__ __forceinline__ void oidxs(int j, int& i0, int& i1, int& i2,
                                      int& i3, int& o) {
    constexpr int TPS = N / 4;
    constexpr int LT = clog2(TPS);
    int s = j >> LT;
    int jj = j & (TPS - 1);
    o = jj & (S - 1);
    int base = s * N + ((jj & ~(S - 1)) << 2) + o;
    i0 = base; i1 = base + S; i2 = base + 2 * S; i3 = base + 3 * S;
}

// Two DIF levels h=2S then h=S (reference args; no aggregates)
template <int S>
__device__ __forceinline__ void difp(float2& A, float2& B, float2& C,
                                     float2& D, int o, const float2* tw) {
    bfly_dif(A, C, tw[o * (32 / S)]);
    bfly_dif(B, D, tw[(o + S) * (32 / S)]);
    float2 wc = tw[o * (64 / S)];
    bfly_dif(A, B, wc);
    bfly_dif(C, D, wc);
}
template <int S>
__device__ __forceinline__ void ditp(float2& A, float2& B, float2& C,
                                     float2& D, int o, const float2* tw) {
    float2 wc = tw[o * (64 / S)];
    bfly_dit(A, B, wc);
    bfly_dit(C, D, wc);
    bfly_dit(A, C, tw[o * (32 / S)]);
    bfly_dit(B, D, tw[(o + S) * (32 / S)]);
}

__device__ __forceinline__ void stf(float* bx, float* by, int a, float2 v) {
    bx[a] = v.x; by[a] = v.y;
}
__device__ __forceinline__ float2 ldf(const float* bx, const float* by, int a) {
    return make_float2(bx[a], by[a]);
}

// One exchange round for a line pair; crew-local (32 lanes of one wave),
// wave_barrier suffices. All scalars/references.
__device__ __forceinline__ void xch2s(float* Xp, float* Yp, int la, int lb,
                                      int w0, int w1, int w2, int w3,
                                      int e0, int e1, int e2, int e3,
                                      float2& A0, float2& A1, float2& A2,
                                      float2& A3, float2& B0, float2& B1,
                                      float2& B2, float2& B3) {
    stf(Xp, Yp, pf(la, w0), A0); stf(Xp, Yp, pf(lb, w0), B0);
    stf(Xp, Yp, pf(la, w1), A1); stf(Xp, Yp, pf(lb, w1), B1);
    stf(Xp, Yp, pf(la, w2), A2); stf(Xp, Yp, pf(lb, w2), B2);
    stf(Xp, Yp, pf(la, w3), A3); stf(Xp, Yp, pf(lb, w3), B3);
    __builtin_amdgcn_wave_barrier();
    A0 = ldf(Xp, Yp, pf(la, e0)); B0 = ldf(Xp, Yp, pf(lb, e0));
    A1 = ldf(Xp, Yp, pf(la, e1)); B1 = ldf(Xp, Yp, pf(lb, e1));
    A2 = ldf(Xp, Yp, pf(la, e2)); B2 = ldf(Xp, Yp, pf(lb, e2));
    A3 = ldf(Xp, Yp, pf(la, e3)); B3 = ldf(Xp, Yp, pf(lb, e3));
    __builtin_amdgcn_wave_barrier();
}

// 2x2 multiplex on feature pair with table entry U[0..3]
__device__ __forceinline__ void muxop(const float2* __restrict__ U,
                                      float2& a, float2& b) {
    float2 p0 = a, p1 = b;
    a = cadd(cmul(U[0], p0), cmul(U[1], p1));
    b = cadd(cmul(U[2], p0), cmul(U[3], p1));
}

// ---- whole-state macros over the 32 named scalars v00..v73 ----------------
#define DIF8(S, O) { \
    difp<S>(v00, v01, v02, v03, O, tw); difp<S>(v10, v11, v12, v13, O, tw); \
    difp<S>(v20, v21, v22, v23, O, tw); difp<S>(v30, v31, v32, v33, O, tw); \
    difp<S>(v40, v41, v42, v43, O, tw); difp<S>(v50, v51, v52, v53, O, tw); \
    difp<S>(v60, v61, v62, v63, O, tw); difp<S>(v70, v71, v72, v73, O, tw); }
#define DIT8(S, O) { \
    ditp<S>(v00, v01, v02, v03, O, tw); ditp<S>(v10, v11, v12, v13, O, tw); \
    ditp<S>(v20, v21, v22, v23, O, tw); ditp<S>(v30, v31, v32, v33, O, tw); \
    ditp<S>(v40, v41, v42, v43, O, tw); ditp<S>(v50, v51, v52, v53, O, tw); \
    ditp<S>(v60, v61, v62, v63, O, tw); ditp<S>(v70, v71, v72, v73, O, tw); }

// exchange of all 8 lines; rounds (0,4),(1,5),(2,6),(3,7) as before
#define XCHC(W0, W1, W2, W3, E0, E1, E2, E3) { \
    xch2s(Xp, Yp, la, lb, W0, W1, W2, W3, E0, E1, E2, E3, \
          v00, v01, v02, v03, v40, v41, v42, v43); \
    xch2s(Xp, Yp, la, lb, W0, W1, W2, W3, E0, E1, E2, E3, \
          v10, v11, v12, v13, v50, v51, v52, v53); \
    xch2s(Xp, Yp, la, lb, W0, W1, W2, W3, E0, E1, E2, E3, \
          v20, v21, v22, v23, v60, v61, v62, v63); \
    xch2s(Xp, Yp, la, lb, W0, W1, W2, W3, E0, E1, E2, E3, \
          v30, v31, v32, v33, v70, v71, v72, v73); }

#define XCALL(NW, SW, NR, SR) { \
    int w0_, w1_, w2_, w3_, e0_, e1_, e2_, e3_, ou_; \
    oidxs<NW, SW>(j, w0_, w1_, w2_, w3_, ou_); (void)ou_; \
    oidxs<NR, SR>(j, e0_, e1_, e2_, e3_, o); \
    XCHC(w0_, w1_, w2_, w3_, e0_, e1_, e2_, e3_) }

#define H1F8() { \
    bfly_dif1(v00, v01); bfly_dif1(v02, v03); bfly_dif1(v10, v11); bfly_dif1(v12, v13); \
    bfly_dif1(v20, v21); bfly_dif1(v22, v23); bfly_dif1(v30, v31); bfly_dif1(v32, v33); \
    bfly_dif1(v40, v41); bfly_dif1(v42, v43); bfly_dif1(v50, v51); bfly_dif1(v52, v53); \
    bfly_dif1(v60, v61); bfly_dif1(v62, v63); bfly_dif1(v70, v71); bfly_dif1(v72, v73); }
#define H1T8() { \
    bfly_dit1(v00, v01); bfly_dit1(v02, v03); bfly_dit1(v10, v11); bfly_dit1(v12, v13); \
    bfly_dit1(v20, v21); bfly_dit1(v22, v23); bfly_dit1(v30, v31); bfly_dit1(v32, v33); \
    bfly_dit1(v40, v41); bfly_dit1(v42, v43); bfly_dit1(v50, v51); bfly_dit1(v52, v53); \
    bfly_dit1(v60, v61); bfly_dit1(v62, v63); bfly_dit1(v70, v71); bfly_dit1(v72, v73); }
#define H64_8(WA, WB) { \
    bfly_dit(v00, v02, WA); bfly_dit(v01, v03, WB); bfly_dit(v10, v12, WA); bfly_dit(v11, v13, WB); \
    bfly_dit(v20, v22, WA); bfly_dit(v21, v23, WB); bfly_dit(v30, v32, WA); bfly_dit(v31, v33, WB); \
    bfly_dit(v40, v42, WA); bfly_dit(v41, v43, WB); bfly_dit(v50, v52, WA); bfly_dit(v51, v53, WB); \
    bfly_dit(v60, v62, WA); bfly_dit(v61, v63, WB); bfly_dit(v70, v72, WA); bfly_dit(v71, v73, WB); }
#define FH8(WC) { \
    bfly_dif(v00, v01, WC); bfly_dif(v02, v03, WC); bfly_dif(v10, v11, WC); bfly_dif(v12, v13, WC); \
    bfly_dif(v20, v21, WC); bfly_dif(v22, v23, WC); bfly_dif(v30, v31, WC); bfly_dif(v32, v33, WC); \
    bfly_dif(v40, v41, WC); bfly_dif(v42, v43, WC); bfly_dif(v50, v51, WC); bfly_dif(v52, v53, WC); \
    bfly_dif(v60, v61, WC); bfly_dif(v62, v63, WC); bfly_dif(v70, v71, WC); bfly_dif(v72, v73, WC); }
#define H16P8(WC) { \
    bfly_dit(v00, v01, WC); bfly_dit(v02, v03, WC); bfly_dit(v10, v11, WC); bfly_dit(v12, v13, WC); \
    bfly_dit(v20, v21, WC); bfly_dit(v22, v23, WC); bfly_dit(v30, v31, WC); bfly_dit(v32, v33, WC); \
    bfly_dit(v40, v41, WC); bfly_dit(v42, v43, WC); bfly_dit(v50, v51, WC); bfly_dit(v52, v53, WC); \
    bfly_dit(v60, v61, WC); bfly_dit(v62, v63, WC); bfly_dit(v70, v71, WC); bfly_dit(v72, v73, WC); }
#define SC8(SCV) { const float sc_ = (SCV); \
    v00 = scl(v00, sc_); v01 = scl(v01, sc_); v02 = scl(v02, sc_); v03 = scl(v03, sc_); \
    v10 = scl(v10, sc_); v11 = scl(v11, sc_); v12 = scl(v12, sc_); v13 = scl(v13, sc_); \
    v20 = scl(v20, sc_); v21 = scl(v21, sc_); v22 = scl(v22, sc_); v23 = scl(v23, sc_); \
    v30 = scl(v30, sc_); v31 = scl(v31, sc_); v32 = scl(v32, sc_); v33 = scl(v33, sc_); \
    v40 = scl(v40, sc_); v41 = scl(v41, sc_); v42 = scl(v42, sc_); v43 = scl(v43, sc_); \
    v50 = scl(v50, sc_); v51 = scl(v51, sc_); v52 = scl(v52, sc_); v53 = scl(v53, sc_); \
    v60 = scl(v60, sc_); v61 = scl(v61, sc_); v62 = scl(v62, sc_); v63 = scl(v63, sc_); \
    v70 = scl(v70, sc_); v71 = scl(v71, sc_); v72 = scl(v72, sc_); v73 = scl(v73, sc_); }

#define SWP(A, B) { float2 t_ = A; A = B; B = t_; }
// register 4x4 transpose per f-block (pure renaming after regalloc)
#define XPOSE44() { \
    SWP(v01, v10) SWP(v02, v20) SWP(v03, v30) SWP(v12, v21) SWP(v13, v31) SWP(v23, v32) \
    SWP(v41, v50) SWP(v42, v60) SWP(v43, v70) SWP(v52, v61) SWP(v53, v71) SWP(v63, v72) }

// Transpose A: store line at Y-positions is0..is3 (rotation swizzle), reload
// at new X line XL with Y positions g+32d.
#define TPA_ST(R0, R1, R2, R3, XL) { const int Xl_ = (XL); \
    int a0_ = Xl_ * P_ + ((is0 + Xl_) & 127); Xp[a0_] = R0.x; Yp[a0_] = R0.y; \
    int a1_ = Xl_ * P_ + ((is1 + Xl_) & 127); Xp[a1_] = R1.x; Yp[a1_] = R1.y; \
    int a2_ = Xl_ * P_ + ((is2 + Xl_) & 127); Xp[a2_] = R2.x; Yp[a2_] = R2.y; \
    int a3_ = Xl_ * P_ + ((is3 + Xl_) & 127); Xp[a3_] = R3.x; Yp[a3_] = R3.y; }
#define TPA_LD(R0, R1, R2, R3, XL) { const int Xl_ = (XL); \
    int a0_ = Xl_ * P_ + ((g + Xl_) & 127);      R0 = make_float2(Xp[a0_], Yp[a0_]); \
    int a1_ = Xl_ * P_ + ((g + 32 + Xl_) & 127); R1 = make_float2(Xp[a1_], Yp[a1_]); \
    int a2_ = Xl_ * P_ + ((g + 64 + Xl_) & 127); R2 = make_float2(Xp[a2_], Yp[a2_]); \
    int a3_ = Xl_ * P_ + ((g + 96 + Xl_) & 127); R3 = make_float2(Xp[a3_], Yp[a3_]); }
#define TPA_CHUNK(RA0, RA1, RA2, RA3, RB0, RB1, RB2, RB3, XLA, XLB) { \
    __syncthreads(); \
    TPA_ST(RA0, RA1, RA2, RA3, g) TPA_ST(RB0, RB1, RB2, RB3, g + 32) \
    __syncthreads(); \
    TPA_LD(RA0, RA1, RA2, RA3, XLA) TPA_LD(RB0, RB1, RB2, RB3, XLB) }

// Transpose B: store line at X-line from is (positions g+32d), reload at
// Y-positions id0..id3.
#define TPB_ST(R0, R1, R2, R3, ISL) { const int Xl_ = (ISL) & 63; \
    int a0_ = Xl_ * P_ + ((g + Xl_) & 127);      Xp[a0_] = R0.x; Yp[a0_] = R0.y; \
    int a1_ = Xl_ * P_ + ((g + 32 + Xl_) & 127); Xp[a1_] = R1.x; Yp[a1_] = R1.y; \
    int a2_ = Xl_ * P_ + ((g + 64 + Xl_) & 127); Xp[a2_] = R2.x; Yp[a2_] = R2.y; \
    int a3_ = Xl_ * P_ + ((g + 96 + Xl_) & 127); Xp[a3_] = R3.x; Yp[a3_] = R3.y; }
#define TPB_LD(R0, R1, R2, R3, XL) { const int Xl_ = (XL); \
    int a0_ = Xl_ * P_ + ((id0 + Xl_) & 127); R0 = make_float2(Xp[a0_], Yp[a0_]); \
    int a1_ = Xl_ * P_ + ((id1 + Xl_) & 127); R1 = make_float2(Xp[a1_], Yp[a1_]); \
    int a2_ = Xl_ * P_ + ((id2 + Xl_) & 127); R2 = make_float2(Xp[a2_], Yp[a2_]); \
    int a3_ = Xl_ * P_ + ((id3 + Xl_) & 127); R3 = make_float2(Xp[a3_], Yp[a3_]); }
#define TPB_CHUNK(RA0, RA1, RA2, RA3, RB0, RB1, RB2, RB3, ISA, ISB) { \
    __syncthreads(); \
    TPB_ST(RA0, RA1, RA2, RA3, ISA) TPB_ST(RB0, RB1, RB2, RB3, ISB) \
    __syncthreads(); \
    TPB_LD(RA0, RA1, RA2, RA3, g) TPB_LD(RB0, RB1, RB2, RB3, g + 32) }

// ---------------------------------------------------------------------------
// K0: precompute multiplex U tables, pre-permuted by bit-reversal (unchanged).
// ---------------------------------------------------------------------------
__global__ __launch_bounds__(256) void k0_prep(const float* __restrict__ mux0,
                                               const float* __restrict__ mux1,
                                               const float* __restrict__ mux2,
                                               float2* __restrict__ U0,
                                               float2* __restrict__ U1,
                                               float2* __restrict__ U2) {
    int t = blockIdx.x * 256 + threadIdx.x;
    const float* src;
    float2* dst;
    if (t < 16384) {
        int xb = t >> 7, yb = t & 127;
        int rx = __brev((unsigned)xb) >> 25;
        int ry = __brev((unsigned)yb) >> 25;
        src = mux0 + ((size_t)rx * 128 + ry) * 3;
        dst = U0 + ((size_t)yb * 128 + xb) * 4;
    } else if (t < 32768) {
        int u = t - 16384;
        int yam = u & 63, xam = (u >> 6) & 63, cy = (u >> 12) & 1, cx = (u >> 13) & 1;
        int rx = __brev((unsigned)xam) >> 26;
        int ry = __brev((unsigned)yam) >> 26;
        src = mux1 + ((size_t)(((cx * 2 + cy) * 64 + rx) * 64 + ry)) * 3;
        dst = U1 + (size_t)u * 4;
    } else if (t < 36864) {
        int u = t - 32768;
        int yam = u & 31, xam = (u >> 5) & 31, cy = (u >> 10) & 1, cx = (u >> 11) & 1;
        int rx = __brev((unsigned)xam) >> 27;
        int ry = __brev((unsigned)yam) >> 27;
        src = mux2 + ((size_t)(((cx * 2 + cy) * 32 + rx) * 32 + ry)) * 3;
        dst = U2 + ((size_t)(((yam * 2 + cx) * 2 + cy) * 32 + xam)) * 4;
    } else {
        return;
    }
    float ax = src[0], ay = src[1], az = src[2];
    float r = sqrtf(ax * ax + ay * ay + az * az + 1e-20f);
    float cr = cosf(r);
    float snr = sinf(r) / r;
    dst[0] = make_float2(cr, -az * snr);
    dst[1] = make_float2(-ay * snr, -ax * snr);
    dst[2] = make_float2(ay * snr, -ax * snr);
    dst[3] = make_float2(cr, az * snr);
}

// ---------------------------------------------------------------------------
// KFUSE: whole pipeline per image. 1024 threads = 32 crews x 32 lanes.
// State = 32 named float2 scalars. Static LDS 82,432 B (1 WG/CU pin).
// ---------------------------------------------------------------------------
__global__ __attribute__((amdgpu_flat_work_group_size(1024, 1024)))
__attribute__((amdgpu_waves_per_eu(4, 4)))
void kfuse(const float* __restrict__ img,
           const float2* __restrict__ U0,
           const float2* __restrict__ U1,
           const float2* __restrict__ U2,
           float* __restrict__ prob) {
    __shared__ float XpS[10240];            // 8192 used + occupancy pad
    __shared__ float YpS[10240];
    __shared__ float2 twS[64];
    float* Xp = XpS;
    float* Yp = YpS;
    float2* tw = twS;

    const int tid = threadIdx.x;
    const int b = blockIdx.x;
    const int g = tid >> 5;
    const int j = tid & 31;
    const int la = 2 * g, lb = 2 * g + 1;

    if (tid < 64) {
        float ang = -(2.0f * PI_F / 128.0f) * (float)tid;  // |ang| < 2pi
        tw[tid] = make_float2(__cosf(ang), __sinf(ang));
    }

    // state: 32 named float2 scalars, vKq = line K, element q
    float2 v00, v01, v02, v03, v10, v11, v12, v13;
    float2 v20, v21, v22, v23, v30, v31, v32, v33;
    float2 v40, v41, v42, v43, v50, v51, v52, v53;
    float2 v60, v61, v62, v63, v70, v71, v72, v73;
    int o;

    // ================= pass 1 (Y): FRQI encode + FFT_Y128 =================
    {
        const float* ib = img + (size_t)b * 16384;
        const float S128 = 1.0f / 128.0f;
#define ENC_K(K, A0, A1, A2, A3, B0, B1, B2, B3) { \
        const float* ip = ib + (g + 32 * (K)) * 128; \
        { float ang = 0.5f * PI_F * ip[j];      A0 = make_float2(__cosf(ang) * S128, 0.0f); B0 = make_float2(__sinf(ang) * S128, 0.0f); } \
        { float ang = 0.5f * PI_F * ip[j + 32]; A1 = make_float2(__cosf(ang) * S128, 0.0f); B1 = make_float2(__sinf(ang) * S128, 0.0f); } \
        { float ang = 0.5f * PI_F * ip[j + 64]; A2 = make_float2(__cosf(ang) * S128, 0.0f); B2 = make_float2(__sinf(ang) * S128, 0.0f); } \
        { float ang = 0.5f * PI_F * ip[j + 96]; A3 = make_float2(__cosf(ang) * S128, 0.0f); B3 = make_float2(__sinf(ang) * S128, 0.0f); } }
        ENC_K(0, v00, v01, v02, v03, v40, v41, v42, v43)
        ENC_K(1, v10, v11, v12, v13, v50, v51, v52, v53)
        ENC_K(2, v20, v21, v22, v23, v60, v61, v62, v63)
        ENC_K(3, v30, v31, v32, v33, v70, v71, v72, v73)
#undef ENC_K
    }
    __syncthreads();  // tw visible
    DIF8(32, j)                                   // h=64,32
    XCALL(128, 32, 128, 8)
    DIF8(8, o)                                    // h=16,8
    XCALL(128, 8, 128, 2)
    DIF8(2, o)                                    // h=4,2
    XCALL(128, 2, 128, 1)
    H1F8()                                        // h=1

    // ================= T_A1 (MODE 0) =================
    {
        const int is0 = 4 * j, is1 = 4 * j + 1, is2 = 4 * j + 2, is3 = 4 * j + 3;
        TPA_CHUNK(v00, v01, v02, v03, v10, v11, v12, v13, j, j + 32)
        TPA_CHUNK(v20, v21, v22, v23, v30, v31, v32, v33, j, j + 32)
        TPA_CHUNK(v40, v41, v42, v43, v50, v51, v52, v53, j, j + 32)
        TPA_CHUNK(v60, v61, v62, v63, v70, v71, v72, v73, j, j + 32)
        __syncthreads();
        XPOSE44()
    }

    // ====== pass 2 (X): FFT_X128 -> M0 -> IFFT_X128 -> FFT_X64 ======
    DIF8(32, j)
    XCALL(128, 32, 128, 8)
    DIF8(8, o)
    XCALL(128, 8, 128, 2)
    DIF8(2, o)
    XCALL(128, 2, 128, 1)
    H1F8()
    // M0 at x_st = 4j+q, y_st = g+32k (register-local f pair)
    {
#define MUX0_K(K, A0, A1, A2, A3, B0, B1, B2, B3) { \
        const float2* Ub = U0 + ((size_t)(g + 32 * (K)) * 128 + 4 * j) * 4; \
        muxop(Ub + 0, A0, B0); muxop(Ub + 4, A1, B1); \
        muxop(Ub + 8, A2, B2); muxop(Ub + 12, A3, B3); }
        MUX0_K(0, v00, v01, v02, v03, v40, v41, v42, v43)
        MUX0_K(1, v10, v11, v12, v13, v50, v51, v52, v53)
        MUX0_K(2, v20, v21, v22, v23, v60, v61, v62, v63)
        MUX0_K(3, v30, v31, v32, v33, v70, v71, v72, v73)
#undef MUX0_K
    }
    // IFFT_X128: [1,2] -> [4,8] -> [16,32] -> [64]
    DIT8(1, 0)
    XCALL(128, 1, 128, 4)
    DIT8(4, o)
    XCALL(128, 4, 128, 16)
    DIT8(16, o)
    XCALL(128, 16, 128, 32)
    { const float2 wA = tw[o], wB = tw[o + 32]; H64_8(wA, wB) }   // h=64
    { const float2 wC = tw[2 * o]; FH8(wC) }                      // FFT64 h=32
    XCALL(128, 32, 64, 8)
    DIF8(8, o)                                    // FFT64 h=16,8
    XCALL(64, 8, 64, 2)
    DIF8(2, o)                                    // h=4,2
    {   // -> F ownership (needed by T_B1)
        int w0_, w1_, w2_, w3_, ou_;
        oidxs<64, 2>(j, w0_, w1_, w2_, w3_, ou_); (void)ou_;
        const int e0_ = 2 * j, e1_ = 2 * j + 1, e2_ = 64 + 2 * j, e3_ = 65 + 2 * j;
        XCHC(w0_, w1_, w2_, w3_, e0_, e1_, e2_, e3_)
    }
    H1F8()                                        // h=1
    SC8(1.0f / 128.0f)                            // IFFT128 norm

    // ================= T_B1 =================
    {
        const int is0 = 2 * j, is1 = 2 * j + 1, is2 = 64 + 2 * j, is3 = 65 + 2 * j;
        const int id0 = 4 * j, id1 = 4 * j + 1, id2 = 4 * j + 2, id3 = 4 * j + 3;
        XPOSE44()
        TPB_CHUNK(v00, v01, v02, v03, v10, v11, v12, v13, is0, is1)
        TPB_CHUNK(v20, v21, v22, v23, v30, v31, v32, v33, is2, is3)
        TPB_CHUNK(v40, v41, v42, v43, v50, v51, v52, v53, is0, is1)
        TPB_CHUNK(v60, v61, v62, v63, v70, v71, v72, v73, is2, is3)
        __syncthreads();
    }

    // == pass 3 (Y): IFFT_Y128 -> FFT_Y64 -> M1 -> IFFT_Y64 -> FFT_Y32 ==
    DIT8(1, 0)
    XCALL(128, 1, 128, 4)
    DIT8(4, o)
    XCALL(128, 4, 128, 16)
    DIT8(16, o)
    XCALL(128, 16, 128, 32)
    { const float2 wA = tw[o], wB = tw[o + 32]; H64_8(wA, wB) }
    { const float2 wC = tw[2 * o]; FH8(wC) }
    XCALL(128, 32, 64, 8)
    DIF8(8, o)
    XCALL(64, 8, 64, 2)
    DIF8(2, o)
    XCALL(64, 2, 64, 1)
    H1F8()
    // M1: y_st = s*64 + 4jj + q; lines x_st = g+32k
    {
        const int s = j >> 4, jj = j & 15;
#define MUX1_K(CX, KB, A0, A1, A2, A3, B0, B1, B2, B3) { \
        const int xam = g + 32 * (KB); \
        const float2* Ub = U1 + \
            ((size_t)(((((((CX) << 1) | s) << 6) | xam) << 6) | (4 * jj))) * 4; \
        muxop(Ub + 0, A0, B0); muxop(Ub + 4, A1, B1); \
        muxop(Ub + 8, A2, B2); muxop(Ub + 12, A3, B3); }
        MUX1_K(0, 0, v00, v01, v02, v03, v40, v41, v42, v43)
        MUX1_K(0, 1, v10, v11, v12, v13, v50, v51, v52, v53)
        MUX1_K(1, 0, v20, v21, v22, v23, v60, v61, v62, v63)
        MUX1_K(1, 1, v30, v31, v32, v33, v70, v71, v72, v73)
#undef MUX1_K
    }
    // IFFT_Y64: [1,2] -> [4,8] -> [16,32]
    DIT8(1, 0)
    XCALL(64, 1, 64, 4)
    DIT8(4, o)
    XCALL(64, 4, 64, 16)
    DIT8(16, o)
    { const float2 wC = tw[4 * o]; FH8(wC) }      // fused FFT32 h=16
    XCALL(64, 16, 32, 4)
    DIF8(4, o)                                    // FFT32 h=8,4
    XCALL(32, 4, 32, 1)
    DIF8(1, 0)                                    // h=2,1
    SC8(1.0f / 8192.0f)                           // IFFT128*IFFT64

    // ================= T_A2 (MODE 1, dest positions = F) =================
    {
        int is0, is1, is2, is3, ou_;
        oidxs<32, 1>(j, is0, is1, is2, is3, ou_); (void)ou_;
        TPA_CHUNK(v00, v01, v02, v03, v10, v11, v12, v13, 2 * j, 2 * j + 1)
        TPA_CHUNK(v20, v21, v22, v23, v30, v31, v32, v33, 2 * j, 2 * j + 1)
        TPA_CHUNK(v40, v41, v42, v43, v50, v51, v52, v53, 2 * j, 2 * j + 1)
        TPA_CHUNK(v60, v61, v62, v63, v70, v71, v72, v73, 2 * j, 2 * j + 1)
        __syncthreads();
        XPOSE44()
    }

    // ====== pass 4 (X): IFFT_X64 -> FFT_X32 -> M2 -> IFFT_X32 ======
    H1T8()                                        // h=1 at F (w=1)
    {
        const int w0_ = 2 * j, w1_ = 2 * j + 1, w2_ = 64 + 2 * j, w3_ = 65 + 2 * j;
        int e0_, e1_, e2_, e3_;
        oidxs<64, 2>(j, e0_, e1_, e2_, e3_, o);
        XCHC(w0_, w1_, w2_, w3_, e0_, e1_, e2_, e3_)
    }
    DIT8(2, o)                                    // h=2,4
    XCALL(64, 2, 64, 8)
    DIT8(8, o)                                    // h=8,16
    XCALL(64, 8, 64, 16)
    { const float2 wA = tw[2 * o], wB = tw[2 * (o + 16)]; H64_8(wA, wB) }  // h=32
    { const float2 wC = tw[4 * o]; FH8(wC) }      // fused FFT32 h=16
    XCALL(64, 16, 32, 4)
    DIF8(4, o)
    XCALL(32, 4, 32, 1)
    DIF8(1, 0)
    // M2: x_st = s4*32 + 4jj8 + q; lines y_st = g+32k
    {
        const int s4 = j >> 3, jj8 = j & 7;
#define MUX2_K(KB, A0, A1, A2, A3, B0, B1, B2, B3) { \
        const float2* Ub = U2 + \
            ((size_t)((((g << 2) | ((s4 & 1) << 1) | (KB)) << 5) | (4 * jj8))) * 4; \
        muxop(Ub + 0, A0, B0); muxop(Ub + 4, A1, B1); \
        muxop(Ub + 8, A2, B2); muxop(Ub + 12, A3, B3); }
        MUX2_K(0, v00, v01, v02, v03, v40, v41, v42, v43)
        MUX2_K(1, v10, v11, v12, v13, v50, v51, v52, v53)
        MUX2_K(0, v20, v21, v22, v23, v60, v61, v62, v63)
        MUX2_K(1, v30, v31, v32, v33, v70, v71, v72, v73)
#undef MUX2_K
    }
    // IFFT_X32: [1,2] -> [4,8] -> [16] (end at F4 for T_B2)
    DIT8(1, 0)
    XCALL(32, 1, 32, 4)
    DIT8(4, o)
    {
        int w0_, w1_, w2_, w3_, ou_;
        oidxs<32, 4>(j, w0_, w1_, w2_, w3_, ou_); (void)ou_;
        const int fb_ = (j >> 4) * 32 + (j & 15);
        const int e0_ = fb_, e1_ = fb_ + 16, e2_ = fb_ + 64, e3_ = fb_ + 80;
        XCHC(w0_, w1_, w2_, w3_, e0_, e1_, e2_, e3_)
    }
    {
        const int m = j & 15;
        const float2 wC = tw[4 * m];
        H16P8(wC)                                 // h=16
        SC8(1.0f / 2048.0f)                       // IFFT64*IFFT32
    }

    // ================= T_B2 =================
    {
        const int fb_ = (j >> 4) * 32 + (j & 15);
        const int is0 = fb_, is1 = fb_ + 16, is2 = fb_ + 64, is3 = fb_ + 80;
        int id0, id1, id2, id3, ou_;
        oidxs<32, 1>(j, id0, id1, id2, id3, ou_); (void)ou_;
        XPOSE44()
        TPB_CHUNK(v00, v01, v02, v03, v10, v11, v12, v13, is0, is1)
        TPB_CHUNK(v20, v21, v22, v23, v30, v31, v32, v33, is2, is3)
        TPB_CHUNK(v40, v41, v42, v43, v50, v51, v52, v53, is0, is1)
        TPB_CHUNK(v60, v61, v62, v63, v70, v71, v72, v73, is2, is3)
        __syncthreads();
    }

    // ========== pass 5 (Y): IFFT_Y32 + |.|^2 marginal ==========
    DIT8(1, 0)
    XCALL(32, 1, 32, 4)
    DIT8(4, o)
    XCALL(32, 4, 32, 8)
    { const float2 wA = tw[4 * o], wB = tw[4 * o + 32]; H64_8(wA, wB) }  // h=16
    // prob: sum over xc (in-thread lines) and yc (= j>>3, via shfl)
    {
#define SQ2(v) ((v).x * (v).x + (v).y * (v).y)
        float s00 = SQ2(v00) + SQ2(v10) + SQ2(v20) + SQ2(v30);
        float s01 = SQ2(v01) + SQ2(v11) + SQ2(v21) + SQ2(v31);
        float s02 = SQ2(v02) + SQ2(v12) + SQ2(v22) + SQ2(v32);
        float s03 = SQ2(v03) + SQ2(v13) + SQ2(v23) + SQ2(v33);
        float s10 = SQ2(v40) + SQ2(v50) + SQ2(v60) + SQ2(v70);
        float s11 = SQ2(v41) + SQ2(v51) + SQ2(v61) + SQ2(v71);
        float s12 = SQ2(v42) + SQ2(v52) + SQ2(v62) + SQ2(v72);
        float s13 = SQ2(v43) + SQ2(v53) + SQ2(v63) + SQ2(v73);
#undef SQ2
        s00 += __shfl_xor(s00, 8); s00 += __shfl_xor(s00, 16);
        s01 += __shfl_xor(s01, 8); s01 += __shfl_xor(s01, 16);
        s02 += __shfl_xor(s02, 8); s02 += __shfl_xor(s02, 16);
        s03 += __shfl_xor(s03, 8); s03 += __shfl_xor(s03, 16);
        s10 += __shfl_xor(s10, 8); s10 += __shfl_xor(s10, 16);
        s11 += __shfl_xor(s11, 8); s11 += __shfl_xor(s11, 16);
        s12 += __shfl_xor(s12, 8); s12 += __shfl_xor(s12, 16);
        s13 += __shfl_xor(s13, 8); s13 += __shfl_xor(s13, 16);
        if ((j >> 3) == 0) {
            const int jj = j & 7;
            const float C = 1.0f / 1024.0f;
            float2* pp = (float2*)(prob + (size_t)(b * 32 + g) * 64);
            pp[jj +  0] = make_float2(s00 * C, s10 * C);
            pp[jj +  8] = make_float2(s01 * C, s11 * C);
            pp[jj + 16] = make_float2(s02 * C, s12 * C);
            pp[jj + 24] = make_float2(s03 * C, s13 * C);
        }
    }
}

// ---------------------------------------------------------------------------
// K6: linear head, wave-shuffle reduction (unchanged).
// ---------------------------------------------------------------------------
__global__ __launch_bounds__(256) void k6_linear(const float* __restrict__ prob,
                                                 const float* __restrict__ W,
                                                 const float* __restrict__ bv,
                                                 float* __restrict__ out) {
    __shared__ float red[40];
    int b = blockIdx.x;
    int tid = threadIdx.x;
    float acc[10];
#pragma unroll
    for (int c = 0; c < 10; ++c) acc[c] = 0.0f;
    for (int j = tid; j < 2048; j += 256) {
        float p = prob[(size_t)b * 2048 + j];
#pragma unroll
        for (int c = 0; c < 10; ++c) acc[c] += p * W[c * 2048 + j];
    }
    int wv = tid >> 6, ln = tid & 63;
#pragma unroll
    for (int c = 0; c < 10; ++c) {
        float s = acc[c];
        for (int off = 32; off > 0; off >>= 1) s += __shfl_down(s, off);
        if (ln == 0) red[wv * 10 + c] = s;
    }
    __syncthreads();
    if (tid < 10)
        out[b * 10 + tid] =
            red[tid] + red[10 + tid] + red[20 + tid] + red[30 + tid] + bv[tid];
}

// ---------------------------------------------------------------------------
extern "C" void kernel_launch(void* const* d_in, const int* in_sizes, int n_in,
                              void* d_out, int out_size, void* d_ws,
                              size_t ws_size, hipStream_t stream) {
    const float* images = (const float*)d_in[0];
    const float* mux0 = (const float*)d_in[1];
    const float* mux1 = (const float*)d_in[2];
    const float* mux2 = (const float*)d_in[3];
    const float* W = (const float*)d_in[4];
    const float* bv = (const float*)d_in[5];
    float* out = (float*)d_out;

    float2* U0 = (float2*)d_ws;
    float2* U1 = U0 + 65536;
    float2* U2 = U1 + 65536;
    float* prob = (float*)(U2 + 16384);
    const size_t needed =
        (size_t)(65536 + 65536 + 16384) * sizeof(float2) +
        (size_t)512 * 2048 * sizeof(float);
    if (ws_size < needed) return;

    k0_prep<<<144, 256, 0, stream>>>(mux0, mux1, mux2, U0, U1, U2);
    kfuse<<<512, 1024, 0, stream>>>(images, U0, U1, U2, prob);
    k6_linear<<<512, 256, 0, stream>>>(prob, W, bv, out);
}

// Round 7
// 353.440 us; speedup vs baseline: 1.1460x; 1.0021x over previous
//
#include <hip/hip_runtime.h>
#include <math.h>

// ===========================================================================
// PCSQCNN fully fused: FRQI encode -> [QFT2D -> mux -> IQFT2D -> pool]^3
//                      -> |.|^2 -> linear
//
// Round 10: fused kfuse (one block/image, 32 float2 state/thread).
// Round 11: waves_per_eu(4,4)       -> null (VGPR 64, scratch stays).
// Round 12: call-free __sinf/__cosf -> null.
// Round 13: scalarized to r0..r7[4] -> null.
// Round 14: static 82KB LDS pin     -> null for VGPR; worse dur (lost the
//   scratch-latency-hiding 2nd WG).
// Round 15: ZERO-AGGREGATE (32 named float2 scalars) -> null. VGPR pinned
//   at 64 across ALL variants => the allocator is budgeting for 8 waves/EU
//   (512/8=64) regardless of occupancy hints; the state is spilled to meet
//   that budget (scratch = sizeof(state)/thread exactly).
// Round 16 (this round): DIRECT REGISTER REQUEST. amdgpu_num_vgpr(128) is
//   the only source-level channel that sets the allocation itself rather
//   than feeding the occupancy heuristic. 128 = max schedulable for a
//   16-wave workgroup (4 waves/SIMD x 128 = full 512-reg file). All else
//   byte-identical to round 15.
//   PRE-COMMITTED PIVOT: if VGPR stays 64, fusion is dead on this
//   toolchain -> next round returns to the split pipeline and optimizes it.
//
// U tables (k0): U0 transposed [y_st][x_st]; U1 unchanged;
// U2 stored [yam][cx][cy][xam] so mux loads are 128B-contiguous/thread.
// Ownerships: F = {2j,2j+1,64+2j,65+2j}; F4 = {fb,fb+16,fb+64,fb+80},
// fb=(j>>4)*32+(j&15).
// ===========================================================================

#define PI_F 3.14159265358979323846f
#define P_ 128

__device__ __forceinline__ float2 cmul(float2 a, float2 b) {
    return make_float2(a.x * b.x - a.y * b.y, a.x * b.y + a.y * b.x);
}
__device__ __forceinline__ float2 cadd(float2 a, float2 b) {
    return make_float2(a.x + b.x, a.y + b.y);
}
__device__ __forceinline__ float2 scl(float2 a, float s) {
    return make_float2(a.x * s, a.y * s);
}
__device__ __forceinline__ void bfly_dif(float2& u, float2& v, float2 w) {
    float tx = u.x - v.x, ty = u.y - v.y;
    u.x += v.x; u.y += v.y;
    v.x = tx * w.x - ty * w.y;
    v.y = tx * w.y + ty * w.x;
}
__device__ __forceinline__ void bfly_dif1(float2& u, float2& v) {
    float tx = u.x - v.x, ty = u.y - v.y;
    u.x += v.x; u.y += v.y;
    v.x = tx; v.y = ty;
}
__device__ __forceinline__ void bfly_dit(float2& u, float2& v, float2 w) {
    float tx = v.x * w.x + v.y * w.y, ty = v.y * w.x - v.x * w.y;
    v.x = u.x - tx; v.y = u.y - ty;
    u.x += tx; u.y += ty;
}
__device__ __forceinline__ void bfly_dit1(float2& u, float2& v) {
    float tx = v.x, ty = v.y;
    v.x = u.x - tx; v.y = u.y - ty;
    u.x += tx; u.y += ty;
}

constexpr int clog2(int v) { return v <= 1 ? 0 : 1 + clog2(v >> 1); }

// LDS exchange address: line L, idx 0..127, XOR bank swizzle (bijective).
__device__ __forceinline__ int pf(int L, int idx) {
    int m = ((idx & 32) ? 13 : 0) ^ ((idx & 64) ? 22 : 0);
    return L * P_ + (idx ^ m);
}

// Ownership (scalar outputs): thread j owns base + {0,1,2,3}*S within
// segment of size N; o = jj % S.
template <int N, int S>
__device__ __forceinline__ void oidxs(int j, int& i0, int& i1, int& i2,
                                      int& i3, int& o) {
    constexpr int TPS = N / 4;
    constexpr int LT = clog2(TPS);
    int s = j >> LT;
    int jj = j & (TPS - 1);
    o = jj & (S - 1);
    int base = s * N + ((jj & ~(S - 1)) << 2) + o;
    i0 = base; i1 = base + S; i2 = base + 2 * S; i3 = base + 3 * S;
}

// Two DIF levels h=2S then h=S (reference args; no aggregates)
template <int S>
__device__ __forceinline__ void difp(float2& A, float2& B, float2& C,
                                     float2& D, int o, const float2* tw) {
    bfly_dif(A, C, tw[o * (32 / S)]);
    bfly_dif(B, D, tw[(o + S) * (32 / S)]);
    float2 wc = tw[o * (64 / S)];
    bfly_dif(A, B, wc);
    bfly_dif(C, D, wc);
}
template <int S>
__device__ __forceinline__ void ditp(float2& A, float2& B, float2& C,
                                     float2& D, int o, const float2* tw) {
    float2 wc = tw[o * (64 / S)];
    bfly_dit(A, B, wc);
    bfly_dit(C, D, wc);
    bfly_dit(A, C, tw[o * (32 / S)]);
    bfly_dit(B, D, tw[(o + S) * (32 / S)]);
}

__device__ __forceinline__ void stf(float* bx, float* by, int a, float2 v) {
    bx[a] = v.x; by[a] = v.y;
}
__device__ __forceinline__ float2 ldf(const float* bx, const float* by, int a) {
    return make_float2(bx[a], by[a]);
}

// One exchange round for a line pair; crew-local (32 lanes of one wave),
// wave_barrier suffices. All scalars/references.
__device__ __forceinline__ void xch2s(float* Xp, float* Yp, int la, int lb,
                                      int w0, int w1, int w2, int w3,
                                      int e0, int e1, int e2, int e3,
                                      float2& A0, float2& A1, float2& A2,
                                      float2& A3, float2& B0, float2& B1,
                                      float2& B2, float2& B3) {
    stf(Xp, Yp, pf(la, w0), A0); stf(Xp, Yp, pf(lb, w0), B0);
    stf(Xp, Yp, pf(la, w1), A1); stf(Xp, Yp, pf(lb, w1), B1);
    stf(Xp, Yp, pf(la, w2), A2); stf(Xp, Yp, pf(lb, w2), B2);
    stf(Xp, Yp, pf(la, w3), A3); stf(Xp, Yp, pf(lb, w3), B3);
    __builtin_amdgcn_wave_barrier();
    A0 = ldf(Xp, Yp, pf(la, e0)); B0 = ldf(Xp, Yp, pf(lb, e0));
    A1 = ldf(Xp, Yp, pf(la, e1)); B1 = ldf(Xp, Yp, pf(lb, e1));
    A2 = ldf(Xp, Yp, pf(la, e2)); B2 = ldf(Xp, Yp, pf(lb, e2));
    A3 = ldf(Xp, Yp, pf(la, e3)); B3 = ldf(Xp, Yp, pf(lb, e3));
    __builtin_amdgcn_wave_barrier();
}

// 2x2 multiplex on feature pair with table entry U[0..3]
__device__ __forceinline__ void muxop(const float2* __restrict__ U,
                                      float2& a, float2& b) {
    float2 p0 = a, p1 = b;
    a = cadd(cmul(U[0], p0), cmul(U[1], p1));
    b = cadd(cmul(U[2], p0), cmul(U[3], p1));
}

// ---- whole-state macros over the 32 named scalars v00..v73 ----------------
#define DIF8(S, O) { \
    difp<S>(v00, v01, v02, v03, O, tw); difp<S>(v10, v11, v12, v13, O, tw); \
    difp<S>(v20, v21, v22, v23, O, tw); difp<S>(v30, v31, v32, v33, O, tw); \
    difp<S>(v40, v41, v42, v43, O, tw); difp<S>(v50, v51, v52, v53, O, tw); \
    difp<S>(v60, v61, v62, v63, O, tw); difp<S>(v70, v71, v72, v73, O, tw); }
#define DIT8(S, O) { \
    ditp<S>(v00, v01, v02, v03, O, tw); ditp<S>(v10, v11, v12, v13, O, tw); \
    ditp<S>(v20, v21, v22, v23, O, tw); ditp<S>(v30, v31, v32, v33, O, tw); \
    ditp<S>(v40, v41, v42, v43, O, tw); ditp<S>(v50, v51, v52, v53, O, tw); \
    ditp<S>(v60, v61, v62, v63, O, tw); ditp<S>(v70, v71, v72, v73, O, tw); }

// exchange of all 8 lines; rounds (0,4),(1,5),(2,6),(3,7) as before
#define XCHC(W0, W1, W2, W3, E0, E1, E2, E3) { \
    xch2s(Xp, Yp, la, lb, W0, W1, W2, W3, E0, E1, E2, E3, \
          v00, v01, v02, v03, v40, v41, v42, v43); \
    xch2s(Xp, Yp, la, lb, W0, W1, W2, W3, E0, E1, E2, E3, \
          v10, v11, v12, v13, v50, v51, v52, v53); \
    xch2s(Xp, Yp, la, lb, W0, W1, W2, W3, E0, E1, E2, E3, \
          v20, v21, v22, v23, v60, v61, v62, v63); \
    xch2s(Xp, Yp, la, lb, W0, W1, W2, W3, E0, E1, E2, E3, \
          v30, v31, v32, v33, v70, v71, v72, v73); }

#define XCALL(NW, SW, NR, SR) { \
    int w0_, w1_, w2_, w3_, e0_, e1_, e2_, e3_, ou_; \
    oidxs<NW, SW>(j, w0_, w1_, w2_, w3_, ou_); (void)ou_; \
    oidxs<NR, SR>(j, e0_, e1_, e2_, e3_, o); \
    XCHC(w0_, w1_, w2_, w3_, e0_, e1_, e2_, e3_) }

#define H1F8() { \
    bfly_dif1(v00, v01); bfly_dif1(v02, v03); bfly_dif1(v10, v11); bfly_dif1(v12, v13); \
    bfly_dif1(v20, v21); bfly_dif1(v22, v23); bfly_dif1(v30, v31); bfly_dif1(v32, v33); \
    bfly_dif1(v40, v41); bfly_dif1(v42, v43); bfly_dif1(v50, v51); bfly_dif1(v52, v53); \
    bfly_dif1(v60, v61); bfly_dif1(v62, v63); bfly_dif1(v70, v71); bfly_dif1(v72, v73); }
#define H1T8() { \
    bfly_dit1(v00, v01); bfly_dit1(v02, v03); bfly_dit1(v10, v11); bfly_dit1(v12, v13); \
    bfly_dit1(v20, v21); bfly_dit1(v22, v23); bfly_dit1(v30, v31); bfly_dit1(v32, v33); \
    bfly_dit1(v40, v41); bfly_dit1(v42, v43); bfly_dit1(v50, v51); bfly_dit1(v52, v53); \
    bfly_dit1(v60, v61); bfly_dit1(v62, v63); bfly_dit1(v70, v71); bfly_dit1(v72, v73); }
#define H64_8(WA, WB) { \
    bfly_dit(v00, v02, WA); bfly_dit(v01, v03, WB); bfly_dit(v10, v12, WA); bfly_dit(v11, v13, WB); \
    bfly_dit(v20, v22, WA); bfly_dit(v21, v23, WB); bfly_dit(v30, v32, WA); bfly_dit(v31, v33, WB); \
    bfly_dit(v40, v42, WA); bfly_dit(v41, v43, WB); bfly_dit(v50, v52, WA); bfly_dit(v51, v53, WB); \
    bfly_dit(v60, v62, WA); bfly_dit(v61, v63, WB); bfly_dit(v70, v72, WA); bfly_dit(v71, v73, WB); }
#define FH8(WC) { \
    bfly_dif(v00, v01, WC); bfly_dif(v02, v03, WC); bfly_dif(v10, v11, WC); bfly_dif(v12, v13, WC); \
    bfly_dif(v20, v21, WC); bfly_dif(v22, v23, WC); bfly_dif(v30, v31, WC); bfly_dif(v32, v33, WC); \
    bfly_dif(v40, v41, WC); bfly_dif(v42, v43, WC); bfly_dif(v50, v51, WC); bfly_dif(v52, v53, WC); \
    bfly_dif(v60, v61, WC); bfly_dif(v62, v63, WC); bfly_dif(v70, v71, WC); bfly_dif(v72, v73, WC); }
#define H16P8(WC) { \
    bfly_dit(v00, v01, WC); bfly_dit(v02, v03, WC); bfly_dit(v10, v11, WC); bfly_dit(v12, v13, WC); \
    bfly_dit(v20, v21, WC); bfly_dit(v22, v23, WC); bfly_dit(v30, v31, WC); bfly_dit(v32, v33, WC); \
    bfly_dit(v40, v41, WC); bfly_dit(v42, v43, WC); bfly_dit(v50, v51, WC); bfly_dit(v52, v53, WC); \
    bfly_dit(v60, v61, WC); bfly_dit(v62, v63, WC); bfly_dit(v70, v71, WC); bfly_dit(v72, v73, WC); }
#define SC8(SCV) { const float sc_ = (SCV); \
    v00 = scl(v00, sc_); v01 = scl(v01, sc_); v02 = scl(v02, sc_); v03 = scl(v03, sc_); \
    v10 = scl(v10, sc_); v11 = scl(v11, sc_); v12 = scl(v12, sc_); v13 = scl(v13, sc_); \
    v20 = scl(v20, sc_); v21 = scl(v21, sc_); v22 = scl(v22, sc_); v23 = scl(v23, sc_); \
    v30 = scl(v30, sc_); v31 = scl(v31, sc_); v32 = scl(v32, sc_); v33 = scl(v33, sc_); \
    v40 = scl(v40, sc_); v41 = scl(v41, sc_); v42 = scl(v42, sc_); v43 = scl(v43, sc_); \
    v50 = scl(v50, sc_); v51 = scl(v51, sc_); v52 = scl(v52, sc_); v53 = scl(v53, sc_); \
    v60 = scl(v60, sc_); v61 = scl(v61, sc_); v62 = scl(v62, sc_); v63 = scl(v63, sc_); \
    v70 = scl(v70, sc_); v71 = scl(v71, sc_); v72 = scl(v72, sc_); v73 = scl(v73, sc_); }

#define SWP(A, B) { float2 t_ = A; A = B; B = t_; }
// register 4x4 transpose per f-block (pure renaming after regalloc)
#define XPOSE44() { \
    SWP(v01, v10) SWP(v02, v20) SWP(v03, v30) SWP(v12, v21) SWP(v13, v31) SWP(v23, v32) \
    SWP(v41, v50) SWP(v42, v60) SWP(v43, v70) SWP(v52, v61) SWP(v53, v71) SWP(v63, v72) }

// Transpose A: store line at Y-positions is0..is3 (rotation swizzle), reload
// at new X line XL with Y positions g+32d.
#define TPA_ST(R0, R1, R2, R3, XL) { const int Xl_ = (XL); \
    int a0_ = Xl_ * P_ + ((is0 + Xl_) & 127); Xp[a0_] = R0.x; Yp[a0_] = R0.y; \
    int a1_ = Xl_ * P_ + ((is1 + Xl_) & 127); Xp[a1_] = R1.x; Yp[a1_] = R1.y; \
    int a2_ = Xl_ * P_ + ((is2 + Xl_) & 127); Xp[a2_] = R2.x; Yp[a2_] = R2.y; \
    int a3_ = Xl_ * P_ + ((is3 + Xl_) & 127); Xp[a3_] = R3.x; Yp[a3_] = R3.y; }
#define TPA_LD(R0, R1, R2, R3, XL) { const int Xl_ = (XL); \
    int a0_ = Xl_ * P_ + ((g + Xl_) & 127);      R0 = make_float2(Xp[a0_], Yp[a0_]); \
    int a1_ = Xl_ * P_ + ((g + 32 + Xl_) & 127); R1 = make_float2(Xp[a1_], Yp[a1_]); \
    int a2_ = Xl_ * P_ + ((g + 64 + Xl_) & 127); R2 = make_float2(Xp[a2_], Yp[a2_]); \
    int a3_ = Xl_ * P_ + ((g + 96 + Xl_) & 127); R3 = make_float2(Xp[a3_], Yp[a3_]); }
#define TPA_CHUNK(RA0, RA1, RA2, RA3, RB0, RB1, RB2, RB3, XLA, XLB) { \
    __syncthreads(); \
    TPA_ST(RA0, RA1, RA2, RA3, g) TPA_ST(RB0, RB1, RB2, RB3, g + 32) \
    __syncthreads(); \
    TPA_LD(RA0, RA1, RA2, RA3, XLA) TPA_LD(RB0, RB1, RB2, RB3, XLB) }

// Transpose B: store line at X-line from is (positions g+32d), reload at
// Y-positions id0..id3.
#define TPB_ST(R0, R1, R2, R3, ISL) { const int Xl_ = (ISL) & 63; \
    int a0_ = Xl_ * P_ + ((g + Xl_) & 127);      Xp[a0_] = R0.x; Yp[a0_] = R0.y; \
    int a1_ = Xl_ * P_ + ((g + 32 + Xl_) & 127); Xp[a1_] = R1.x; Yp[a1_] = R1.y; \
    int a2_ = Xl_ * P_ + ((g + 64 + Xl_) & 127); Xp[a2_] = R2.x; Yp[a2_] = R2.y; \
    int a3_ = Xl_ * P_ + ((g + 96 + Xl_) & 127); Xp[a3_] = R3.x; Yp[a3_] = R3.y; }
#define TPB_LD(R0, R1, R2, R3, XL) { const int Xl_ = (XL); \
    int a0_ = Xl_ * P_ + ((id0 + Xl_) & 127); R0 = make_float2(Xp[a0_], Yp[a0_]); \
    int a1_ = Xl_ * P_ + ((id1 + Xl_) & 127); R1 = make_float2(Xp[a1_], Yp[a1_]); \
    int a2_ = Xl_ * P_ + ((id2 + Xl_) & 127); R2 = make_float2(Xp[a2_], Yp[a2_]); \
    int a3_ = Xl_ * P_ + ((id3 + Xl_) & 127); R3 = make_float2(Xp[a3_], Yp[a3_]); }
#define TPB_CHUNK(RA0, RA1, RA2, RA3, RB0, RB1, RB2, RB3, ISA, ISB) { \
    __syncthreads(); \
    TPB_ST(RA0, RA1, RA2, RA3, ISA) TPB_ST(RB0, RB1, RB2, RB3, ISB) \
    __syncthreads(); \
    TPB_LD(RA0, RA1, RA2, RA3, g) TPB_LD(RB0, RB1, RB2, RB3, g + 32) }

// ---------------------------------------------------------------------------
// K0: precompute multiplex U tables, pre-permuted by bit-reversal (unchanged).
// ---------------------------------------------------------------------------
__global__ __launch_bounds__(256) void k0_prep(const float* __restrict__ mux0,
                                               const float* __restrict__ mux1,
                                               const float* __restrict__ mux2,
                                               float2* __restrict__ U0,
                                               float2* __restrict__ U1,
                                               float2* __restrict__ U2) {
    int t = blockIdx.x * 256 + threadIdx.x;
    const float* src;
    float2* dst;
    if (t < 16384) {
        int xb = t >> 7, yb = t & 127;
        int rx = __brev((unsigned)xb) >> 25;
        int ry = __brev((unsigned)yb) >> 25;
        src = mux0 + ((size_t)rx * 128 + ry) * 3;
        dst = U0 + ((size_t)yb * 128 + xb) * 4;
    } else if (t < 32768) {
        int u = t - 16384;
        int yam = u & 63, xam = (u >> 6) & 63, cy = (u >> 12) & 1, cx = (u >> 13) & 1;
        int rx = __brev((unsigned)xam) >> 26;
        int ry = __brev((unsigned)yam) >> 26;
        src = mux1 + ((size_t)(((cx * 2 + cy) * 64 + rx) * 64 + ry)) * 3;
        dst = U1 + (size_t)u * 4;
    } else if (t < 36864) {
        int u = t - 32768;
        int yam = u & 31, xam = (u >> 5) & 31, cy = (u >> 10) & 1, cx = (u >> 11) & 1;
        int rx = __brev((unsigned)xam) >> 27;
        int ry = __brev((unsigned)yam) >> 27;
        src = mux2 + ((size_t)(((cx * 2 + cy) * 32 + rx) * 32 + ry)) * 3;
        dst = U2 + ((size_t)(((yam * 2 + cx) * 2 + cy) * 32 + xam)) * 4;
    } else {
        return;
    }
    float ax = src[0], ay = src[1], az = src[2];
    float r = sqrtf(ax * ax + ay * ay + az * az + 1e-20f);
    float cr = cosf(r);
    float snr = sinf(r) / r;
    dst[0] = make_float2(cr, -az * snr);
    dst[1] = make_float2(-ay * snr, -ax * snr);
    dst[2] = make_float2(ay * snr, -ax * snr);
    dst[3] = make_float2(cr, az * snr);
}

// ---------------------------------------------------------------------------
// KFUSE: whole pipeline per image. 1024 threads = 32 crews x 32 lanes.
// State = 32 named float2 scalars. Static LDS 82,432 B (1 WG/CU pin).
// amdgpu_num_vgpr(128): direct allocation request (max schedulable for a
// 16-wave workgroup) — round-16 decisive experiment.
// ---------------------------------------------------------------------------
__global__ __attribute__((amdgpu_flat_work_group_size(1024, 1024)))
__attribute__((amdgpu_num_vgpr(128)))
void kfuse(const float* __restrict__ img,
           const float2* __restrict__ U0,
           const float2* __restrict__ U1,
           const float2* __restrict__ U2,
           float* __restrict__ prob) {
    __shared__ float XpS[10240];            // 8192 used + occupancy pad
    __shared__ float YpS[10240];
    __shared__ float2 twS[64];
    float* Xp = XpS;
    float* Yp = YpS;
    float2* tw = twS;

    const int tid = threadIdx.x;
    const int b = blockIdx.x;
    const int g = tid >> 5;
    const int j = tid & 31;
    const int la = 2 * g, lb = 2 * g + 1;

    if (tid < 64) {
        float ang = -(2.0f * PI_F / 128.0f) * (float)tid;  // |ang| < 2pi
        tw[tid] = make_float2(__cosf(ang), __sinf(ang));
    }

    // state: 32 named float2 scalars, vKq = line K, element q
    float2 v00, v01, v02, v03, v10, v11, v12, v13;
    float2 v20, v21, v22, v23, v30, v31, v32, v33;
    float2 v40, v41, v42, v43, v50, v51, v52, v53;
    float2 v60, v61, v62, v63, v70, v71, v72, v73;
    int o;

    // ================= pass 1 (Y): FRQI encode + FFT_Y128 =================
    {
        const float* ib = img + (size_t)b * 16384;
        const float S128 = 1.0f / 128.0f;
#define ENC_K(K, A0, A1, A2, A3, B0, B1, B2, B3) { \
        const float* ip = ib + (g + 32 * (K)) * 128; \
        { float ang = 0.5f * PI_F * ip[j];      A0 = make_float2(__cosf(ang) * S128, 0.0f); B0 = make_float2(__sinf(ang) * S128, 0.0f); } \
        { float ang = 0.5f * PI_F * ip[j + 32]; A1 = make_float2(__cosf(ang) * S128, 0.0f); B1 = make_float2(__sinf(ang) * S128, 0.0f); } \
        { float ang = 0.5f * PI_F * ip[j + 64]; A2 = make_float2(__cosf(ang) * S128, 0.0f); B2 = make_float2(__sinf(ang) * S128, 0.0f); } \
        { float ang = 0.5f * PI_F * ip[j + 96]; A3 = make_float2(__cosf(ang) * S128, 0.0f); B3 = make_float2(__sinf(ang) * S128, 0.0f); } }
        ENC_K(0, v00, v01, v02, v03, v40, v41, v42, v43)
        ENC_K(1, v10, v11, v12, v13, v50, v51, v52, v53)
        ENC_K(2, v20, v21, v22, v23, v60, v61, v62, v63)
        ENC_K(3, v30, v31, v32, v33, v70, v71, v72, v73)
#undef ENC_K
    }
    __syncthreads();  // tw visible
    DIF8(32, j)                                   // h=64,32
    XCALL(128, 32, 128, 8)
    DIF8(8, o)                                    // h=16,8
    XCALL(128, 8, 128, 2)
    DIF8(2, o)                                    // h=4,2
    XCALL(128, 2, 128, 1)
    H1F8()                                        // h=1

    // ================= T_A1 (MODE 0) =================
    {
        const int is0 = 4 * j, is1 = 4 * j + 1, is2 = 4 * j + 2, is3 = 4 * j + 3;
        TPA_CHUNK(v00, v01, v02, v03, v10, v11, v12, v13, j, j + 32)
        TPA_CHUNK(v20, v21, v22, v23, v30, v31, v32, v33, j, j + 32)
        TPA_CHUNK(v40, v41, v42, v43, v50, v51, v52, v53, j, j + 32)
        TPA_CHUNK(v60, v61, v62, v63, v70, v71, v72, v73, j, j + 32)
        __syncthreads();
        XPOSE44()
    }

    // ====== pass 2 (X): FFT_X128 -> M0 -> IFFT_X128 -> FFT_X64 ======
    DIF8(32, j)
    XCALL(128, 32, 128, 8)
    DIF8(8, o)
    XCALL(128, 8, 128, 2)
    DIF8(2, o)
    XCALL(128, 2, 128, 1)
    H1F8()
    // M0 at x_st = 4j+q, y_st = g+32k (register-local f pair)
    {
#define MUX0_K(K, A0, A1, A2, A3, B0, B1, B2, B3) { \
        const float2* Ub = U0 + ((size_t)(g + 32 * (K)) * 128 + 4 * j) * 4; \
        muxop(Ub + 0, A0, B0); muxop(Ub + 4, A1, B1); \
        muxop(Ub + 8, A2, B2); muxop(Ub + 12, A3, B3); }
        MUX0_K(0, v00, v01, v02, v03, v40, v41, v42, v43)
        MUX0_K(1, v10, v11, v12, v13, v50, v51, v52, v53)
        MUX0_K(2, v20, v21, v22, v23, v60, v61, v62, v63)
        MUX0_K(3, v30, v31, v32, v33, v70, v71, v72, v73)
#undef MUX0_K
    }
    // IFFT_X128: [1,2] -> [4,8] -> [16,32] -> [64]
    DIT8(1, 0)
    XCALL(128, 1, 128, 4)
    DIT8(4, o)
    XCALL(128, 4, 128, 16)
    DIT8(16, o)
    XCALL(128, 16, 128, 32)
    { const float2 wA = tw[o], wB = tw[o + 32]; H64_8(wA, wB) }   // h=64
    { const float2 wC = tw[2 * o]; FH8(wC) }                      // FFT64 h=32
    XCALL(128, 32, 64, 8)
    DIF8(8, o)                                    // FFT64 h=16,8
    XCALL(64, 8, 64, 2)
    DIF8(2, o)                                    // h=4,2
    {   // -> F ownership (needed by T_B1)
        int w0_, w1_, w2_, w3_, ou_;
        oidxs<64, 2>(j, w0_, w1_, w2_, w3_, ou_); (void)ou_;
        const int e0_ = 2 * j, e1_ = 2 * j + 1, e2_ = 64 + 2 * j, e3_ = 65 + 2 * j;
        XCHC(w0_, w1_, w2_, w3_, e0_, e1_, e2_, e3_)
    }
    H1F8()                                        // h=1
    SC8(1.0f / 128.0f)                            // IFFT128 norm

    // ================= T_B1 =================
    {
        const int is0 = 2 * j, is1 = 2 * j + 1, is2 = 64 + 2 * j, is3 = 65 + 2 * j;
        const int id0 = 4 * j, id1 = 4 * j + 1, id2 = 4 * j + 2, id3 = 4 * j + 3;
        XPOSE44()
        TPB_CHUNK(v00, v01, v02, v03, v10, v11, v12, v13, is0, is1)
        TPB_CHUNK(v20, v21, v22, v23, v30, v31, v32, v33, is2, is3)
        TPB_CHUNK(v40, v41, v42, v43, v50, v51, v52, v53, is0, is1)
        TPB_CHUNK(v60, v61, v62, v63, v70, v71, v72, v73, is2, is3)
        __syncthreads();
    }

    // == pass 3 (Y): IFFT_Y128 -> FFT_Y64 -> M1 -> IFFT_Y64 -> FFT_Y32 ==
    DIT8(1, 0)
    XCALL(128, 1, 128, 4)
    DIT8(4, o)
    XCALL(128, 4, 128, 16)
    DIT8(16, o)
    XCALL(128, 16, 128, 32)
    { const float2 wA = tw[o], wB = tw[o + 32]; H64_8(wA, wB) }
    { const float2 wC = tw[2 * o]; FH8(wC) }
    XCALL(128, 32, 64, 8)
    DIF8(8, o)
    XCALL(64, 8, 64, 2)
    DIF8(2, o)
    XCALL(64, 2, 64, 1)
    H1F8()
    // M1: y_st = s*64 + 4jj + q; lines x_st = g+32k
    {
        const int s = j >> 4, jj = j & 15;
#define MUX1_K(CX, KB, A0, A1, A2, A3, B0, B1, B2, B3) { \
        const int xam = g + 32 * (KB); \
        const float2* Ub = U1 + \
            ((size_t)(((((((CX) << 1) | s) << 6) | xam) << 6) | (4 * jj))) * 4; \
        muxop(Ub + 0, A0, B0); muxop(Ub + 4, A1, B1); \
        muxop(Ub + 8, A2, B2); muxop(Ub + 12, A3, B3); }
        MUX1_K(0, 0, v00, v01, v02, v03, v40, v41, v42, v43)
        MUX1_K(0, 1, v10, v11, v12, v13, v50, v51, v52, v53)
        MUX1_K(1, 0, v20, v21, v22, v23, v60, v61, v62, v63)
        MUX1_K(1, 1, v30, v31, v32, v33, v70, v71, v72, v73)
#undef MUX1_K
    }
    // IFFT_Y64: [1,2] -> [4,8] -> [16,32]
    DIT8(1, 0)
    XCALL(64, 1, 64, 4)
    DIT8(4, o)
    XCALL(64, 4, 64, 16)
    DIT8(16, o)
    { const float2 wC = tw[4 * o]; FH8(wC) }      // fused FFT32 h=16
    XCALL(64, 16, 32, 4)
    DIF8(4, o)                                    // FFT32 h=8,4
    XCALL(32, 4, 32, 1)
    DIF8(1, 0)                                    // h=2,1
    SC8(1.0f / 8192.0f)                           // IFFT128*IFFT64

    // ================= T_A2 (MODE 1, dest positions = F) =================
    {
        int is0, is1, is2, is3, ou_;
        oidxs<32, 1>(j, is0, is1, is2, is3, ou_); (void)ou_;
        TPA_CHUNK(v00, v01, v02, v03, v10, v11, v12, v13, 2 * j, 2 * j + 1)
        TPA_CHUNK(v20, v21, v22, v23, v30, v31, v32, v33, 2 * j, 2 * j + 1)
        TPA_CHUNK(v40, v41, v42, v43, v50, v51, v52, v53, 2 * j, 2 * j + 1)
        TPA_CHUNK(v60, v61, v62, v63, v70, v71, v72, v73, 2 * j, 2 * j + 1)
        __syncthreads();
        XPOSE44()
    }

    // ====== pass 4 (X): IFFT_X64 -> FFT_X32 -> M2 -> IFFT_X32 ======
    H1T8()                                        // h=1 at F (w=1)
    {
        const int w0_ = 2 * j, w1_ = 2 * j + 1, w2_ = 64 + 2 * j, w3_ = 65 + 2 * j;
        int e0_, e1_, e2_, e3_;
        oidxs<64, 2>(j, e0_, e1_, e2_, e3_, o);
        XCHC(w0_, w1_, w2_, w3_, e0_, e1_, e2_, e3_)
    }
    DIT8(2, o)                                    // h=2,4
    XCALL(64, 2, 64, 8)
    DIT8(8, o)                                    // h=8,16
    XCALL(64, 8, 64, 16)
    { const float2 wA = tw[2 * o], wB = tw[2 * (o + 16)]; H64_8(wA, wB) }  // h=32
    { const float2 wC = tw[4 * o]; FH8(wC) }      // fused FFT32 h=16
    XCALL(64, 16, 32, 4)
    DIF8(4, o)
    XCALL(32, 4, 32, 1)
    DIF8(1, 0)
    // M2: x_st = s4*32 + 4jj8 + q; lines y_st = g+32k
    {
        const int s4 = j >> 3, jj8 = j & 7;
#define MUX2_K(KB, A0, A1, A2, A3, B0, B1, B2, B3) { \
        const float2* Ub = U2 + \
            ((size_t)((((g << 2) | ((s4 & 1) << 1) | (KB)) << 5) | (4 * jj8))) * 4; \
        muxop(Ub + 0, A0, B0); muxop(Ub + 4, A1, B1); \
        muxop(Ub + 8, A2, B2); muxop(Ub + 12, A3, B3); }
        MUX2_K(0, v00, v01, v02, v03, v40, v41, v42, v43)
        MUX2_K(1, v10, v11, v12, v13, v50, v51, v52, v53)
        MUX2_K(0, v20, v21, v22, v23, v60, v61, v62, v63)
        MUX2_K(1, v30, v31, v32, v33, v70, v71, v72, v73)
#undef MUX2_K
    }
    // IFFT_X32: [1,2] -> [4,8] -> [16] (end at F4 for T_B2)
    DIT8(1, 0)
    XCALL(32, 1, 32, 4)
    DIT8(4, o)
    {
        int w0_, w1_, w2_, w3_, ou_;
        oidxs<32, 4>(j, w0_, w1_, w2_, w3_, ou_); (void)ou_;
        const int fb_ = (j >> 4) * 32 + (j & 15);
        const int e0_ = fb_, e1_ = fb_ + 16, e2_ = fb_ + 64, e3_ = fb_ + 80;
        XCHC(w0_, w1_, w2_, w3_, e0_, e1_, e2_, e3_)
    }
    {
        const int m = j & 15;
        const float2 wC = tw[4 * m];
        H16P8(wC)                                 // h=16
        SC8(1.0f / 2048.0f)                       // IFFT64*IFFT32
    }

    // ================= T_B2 =================
    {
        const int fb_ = (j >> 4) * 32 + (j & 15);
        const int is0 = fb_, is1 = fb_ + 16, is2 = fb_ + 64, is3 = fb_ + 80;
        int id0, id1, id2, id3, ou_;
        oidxs<32, 1>(j, id0, id1, id2, id3, ou_); (void)ou_;
        XPOSE44()
        TPB_CHUNK(v00, v01, v02, v03, v10, v11, v12, v13, is0, is1)
        TPB_CHUNK(v20, v21, v22, v23, v30, v31, v32, v33, is2, is3)
        TPB_CHUNK(v40, v41, v42, v43, v50, v51, v52, v53, is0, is1)
        TPB_CHUNK(v60, v61, v62, v63, v70, v71, v72, v73, is2, is3)
        __syncthreads();
    }

    // ========== pass 5 (Y): IFFT_Y32 + |.|^2 marginal ==========
    DIT8(1, 0)
    XCALL(32, 1, 32, 4)
    DIT8(4, o)
    XCALL(32, 4, 32, 8)
    { const float2 wA = tw[4 * o], wB = tw[4 * o + 32]; H64_8(wA, wB) }  // h=16
    // prob: sum over xc (in-thread lines) and yc (= j>>3, via shfl)
    {
#define SQ2(v) ((v).x * (v).x + (v).y * (v).y)
        float s00 = SQ2(v00) + SQ2(v10) + SQ2(v20) + SQ2(v30);
        float s01 = SQ2(v01) + SQ2(v11) + SQ2(v21) + SQ2(v31);
        float s02 = SQ2(v02) + SQ2(v12) + SQ2(v22) + SQ2(v32);
        float s03 = SQ2(v03) + SQ2(v13) + SQ2(v23) + SQ2(v33);
        float s10 = SQ2(v40) + SQ2(v50) + SQ2(v60) + SQ2(v70);
        float s11 = SQ2(v41) + SQ2(v51) + SQ2(v61) + SQ2(v71);
        float s12 = SQ2(v42) + SQ2(v52) + SQ2(v62) + SQ2(v72);
        float s13 = SQ2(v43) + SQ2(v53) + SQ2(v63) + SQ2(v73);
#undef SQ2
        s00 += __shfl_xor(s00, 8); s00 += __shfl_xor(s00, 16);
        s01 += __shfl_xor(s01, 8); s01 += __shfl_xor(s01, 16);
        s02 += __shfl_xor(s02, 8); s02 += __shfl_xor(s02, 16);
        s03 += __shfl_xor(s03, 8); s03 += __shfl_xor(s03, 16);
        s10 += __shfl_xor(s10, 8); s10 += __shfl_xor(s10, 16);
        s11 += __shfl_xor(s11, 8); s11 += __shfl_xor(s11, 16);
        s12 += __shfl_xor(s12, 8); s12 += __shfl_xor(s12, 16);
        s13 += __shfl_xor(s13, 8); s13 += __shfl_xor(s13, 16);
        if ((j >> 3) == 0) {
            const int jj = j & 7;
            const float C = 1.0f / 1024.0f;
            float2* pp = (float2*)(prob + (size_t)(b * 32 + g) * 64);
            pp[jj +  0] = make_float2(s00 * C, s10 * C);
            pp[jj +  8] = make_float2(s01 * C, s11 * C);
            pp[jj + 16] = make_float2(s02 * C, s12 * C);
            pp[jj + 24] = make_float2(s03 * C, s13 * C);
        }
    }
}

// ---------------------------------------------------------------------------
// K6: linear head, wave-shuffle reduction (unchanged).
// ---------------------------------------------------------------------------
__global__ __launch_bounds__(256) void k6_linear(const float* __restrict__ prob,
                                                 const float* __restrict__ W,
                                                 const float* __restrict__ bv,
                                                 float* __restrict__ out) {
    __shared__ float red[40];
    int b = blockIdx.x;
    int tid = threadIdx.x;
    float acc[10];
#pragma unroll
    for (int c = 0; c < 10; ++c) acc[c] = 0.0f;
    for (int j = tid; j < 2048; j += 256) {
        float p = prob[(size_t)b * 2048 + j];
#pragma unroll
        for (int c = 0; c < 10; ++c) acc[c] += p * W[c * 2048 + j];
    }
    int wv = tid >> 6, ln = tid & 63;
#pragma unroll
    for (int c = 0; c < 10; ++c) {
        float s = acc[c];
        for (int off = 32; off > 0; off >>= 1) s += __shfl_down(s, off);
        if (ln == 0) red[wv * 10 + c] = s;
    }
    __syncthreads();
    if (tid < 10)
        out[b * 10 + tid] =
            red[tid] + red[10 + tid] + red[20 + tid] + red[30 + tid] + bv[tid];
}

// ---------------------------------------------------------------------------
extern "C" void kernel_launch(void* const* d_in, const int* in_sizes, int n_in,
                              void* d_out, int out_size, void* d_ws,
                              size_t ws_size, hipStream_t stream) {
    const float* images = (const float*)d_in[0];
    const float* mux0 = (const float*)d_in[1];
    const float* mux1 = (const float*)d_in[2];
    const float* mux2 = (const float*)d_in[3];
    const float* W = (const float*)d_in[4];
    const float* bv = (const float*)d_in[5];
    float* out = (float*)d_out;

    float2* U0 = (float2*)d_ws;
    float2* U1 = U0 + 65536;
    float2* U2 = U1 + 65536;
    float* prob = (float*)(U2 + 16384);
    const size_t needed =
        (size_t)(65536 + 65536 + 16384) * sizeof(float2) +
        (size_t)512 * 2048 * sizeof(float);
    if (ws_size < needed) return;

    k0_prep<<<144, 256, 0, stream>>>(mux0, mux1, mux2, U0, U1, U2);
    kfuse<<<512, 1024, 0, stream>>>(images, U0, U1, U2, prob);
    k6_linear<<<512, 256, 0, stream>>>(prob, W, bv, out);
}